// Round 1
// baseline (85.806 us; speedup 1.0000x reference)
//
#include <hip/hip_runtime.h>
#include <hip/hip_bf16.h>
#include <math.h>

#define BN 32
#define XLEN 1024
#define COLS 512
#define ROWS (BN * XLEN)   // 32768
#define STAB 1e-15

// ---------------------------------------------------------------------------
// Kernel 1: softmax (f32) -> min-max normalize (f32) -> weighted Gaussian fit
// (f64), one wave (64 lanes) per row, 8 columns per lane, shuffle reductions.
// Writes mu (f32) and sigma (f32) per row into workspace.
// ---------------------------------------------------------------------------
__global__ __launch_bounds__(256) void gaus_fit_kernel(
    const float* __restrict__ x, float* __restrict__ mu_out,
    float* __restrict__ sig_out) {
  const int lane = threadIdx.x & 63;
  const int wid  = threadIdx.x >> 6;
  const int row  = blockIdx.x * 4 + wid;
  if (row >= ROWS) return;

  const float4* rp = (const float4*)(x + (size_t)row * COLS);
  float4 v0 = rp[lane];        // cols lane*4 .. lane*4+3
  float4 v1 = rp[lane + 64];   // cols 256+lane*4 .. 256+lane*4+3
  float xv[8] = {v0.x, v0.y, v0.z, v0.w, v1.x, v1.y, v1.z, v1.w};

  // row max (f32)
  float mx = xv[0];
#pragma unroll
  for (int k = 1; k < 8; ++k) mx = fmaxf(mx, xv[k]);
#pragma unroll
  for (int m = 32; m >= 1; m >>= 1) mx = fmaxf(mx, __shfl_xor(mx, m, 64));

  // exp and sum (f32)
  float e[8];
  float S = 0.0f;
#pragma unroll
  for (int k = 0; k < 8; ++k) {
    e[k] = expf(xv[k] - mx);
    S += e[k];
  }
#pragma unroll
  for (int m = 32; m >= 1; m >>= 1) S += __shfl_xor(S, m, 64);

  // p = e / S; reduce min / max of p (f32)
  float p[8];
  float pmin = 3.0e38f, pmax = -3.0e38f;
#pragma unroll
  for (int k = 0; k < 8; ++k) {
    p[k] = e[k] / S;
    pmin = fminf(pmin, p[k]);
    pmax = fmaxf(pmax, p[k]);
  }
#pragma unroll
  for (int m = 32; m >= 1; m >>= 1) {
    pmin = fminf(pmin, __shfl_xor(pmin, m, 64));
    pmax = fmaxf(pmax, __shfl_xor(pmax, m, 64));
  }
  const float denom = pmax - pmin;

  // f64 weighted sums
  double s_y2 = 0.0, s_xy2 = 0.0, s_x2y2 = 0.0, s_x3y2 = 0.0, s_x4y2 = 0.0;
  double s_y2l = 0.0, s_xy2l = 0.0, s_x2y2l = 0.0;
#pragma unroll
  for (int k = 0; k < 8; ++k) {
    const int col = (k < 4) ? (lane * 4 + k) : (256 + lane * 4 + (k - 4));
    const float pn = (p[k] - pmin) / denom + 0.001f;
    const double y  = (double)pn;
    const double y2 = y * y;
    const double l  = log(y);
    const double y2l = y2 * l;
    const double x1 = (double)col;
    const double x2 = x1 * x1;
    const double x3 = x2 * x1;
    const double x4 = x2 * x2;
    s_y2    += y2;
    s_xy2   += x1 * y2;
    s_x2y2  += x2 * y2;
    s_x3y2  += x3 * y2;
    s_x4y2  += x4 * y2;
    s_y2l   += y2l;
    s_xy2l  += x1 * y2l;
    s_x2y2l += x2 * y2l;
  }
#pragma unroll
  for (int m = 32; m >= 1; m >>= 1) {
    s_y2    += __shfl_xor(s_y2, m, 64);
    s_xy2   += __shfl_xor(s_xy2, m, 64);
    s_x2y2  += __shfl_xor(s_x2y2, m, 64);
    s_x3y2  += __shfl_xor(s_x3y2, m, 64);
    s_x4y2  += __shfl_xor(s_x4y2, m, 64);
    s_y2l   += __shfl_xor(s_y2l, m, 64);
    s_xy2l  += __shfl_xor(s_xy2l, m, 64);
    s_x2y2l += __shfl_xor(s_x2y2l, m, 64);
  }

  if (lane == 0) {
    const double A2 = s_x2y2 * s_x2y2;
    double b_num = A2 * s_xy2l - s_y2 * s_x4y2 * s_xy2l
                 + s_xy2 * s_x4y2 * s_y2l + s_y2 * s_x3y2 * s_x2y2l
                 - s_x2y2 * s_x3y2 * s_y2l - s_xy2 * s_x2y2 * s_x2y2l;
    double c_num = s_x2y2l * s_xy2 * s_xy2 - s_xy2l * s_xy2 * s_x2y2
                 - s_x3y2 * s_y2l * s_xy2 + s_y2l * A2
                 - s_y2 * s_x2y2l * s_x2y2 + s_y2 * s_x3y2 * s_xy2l;
    if (fabs(c_num) < STAB) {
      c_num = (c_num > 0.0) ? STAB : ((c_num < 0.0) ? -STAB : 0.0);
    }
    const double mu = -b_num / (2.0 * c_num);
    const double c_din = s_x4y2 * s_xy2 * s_xy2
                       - 2.0 * s_xy2 * s_x2y2 * s_x3y2 + s_x2y2 * A2
                       - s_y2 * s_x4y2 * s_x2y2 + s_y2 * s_x3y2 * s_x3y2;
    double sigma = -0.5 * c_din / c_num;
    if (sigma < 1.0) sigma = 1.0;  // NaN stays NaN, matching jnp.where
    mu_out[row]  = (float)mu;
    sig_out[row] = (float)sigma;
  }
}

// ---------------------------------------------------------------------------
// Kernel 2: per-batch tridiagonal solve via parallel cyclic reduction (f64).
// Matrix: hess_pair (tridiag, f32 entries from w) + diag(1/sigma) (f32).
// One block of 1024 threads per batch (n = XLEN = 1024), 10 PCR steps.
// ---------------------------------------------------------------------------
__global__ __launch_bounds__(1024) void pcr_solve_kernel(
    const float* __restrict__ mu, const float* __restrict__ sigma,
    const float* __restrict__ w_comp, float* __restrict__ out) {
  __shared__ double A[XLEN], B[XLEN], C[XLEN], D[XLEN];
  const int i = threadIdx.x;
  const int g = blockIdx.x * XLEN + i;

  const float w = w_comp[0];
  const float offf  = -2.0f * w;
  const float mainw = (i == 0 || i == XLEN - 1) ? (2.0f * w) : (4.0f * w);
  const float sr = 1.0f / sigma[g];      // f32, matches reference
  const float bf = mainw + sr;           // f32 diag entry, matches hess build
  const float df = mu[g] * sr;           // f32 rhs, matches p = mean*sig_rev

  A[i] = (i == 0) ? 0.0 : (double)offf;
  C[i] = (i == XLEN - 1) ? 0.0 : (double)offf;
  B[i] = (double)bf;
  D[i] = (double)df;
  __syncthreads();

  for (int s = 1; s < XLEN; s <<= 1) {
    const double ai = A[i], bi = B[i], ci = C[i], di = D[i];
    double am = 0.0, cm = 0.0, dm = 0.0, bm = 1.0;
    double ap = 0.0, cp = 0.0, dp = 0.0, bp = 1.0;
    if (i >= s)        { am = A[i - s]; bm = B[i - s]; cm = C[i - s]; dm = D[i - s]; }
    if (i + s < XLEN)  { ap = A[i + s]; bp = B[i + s]; cp = C[i + s]; dp = D[i + s]; }
    const double k1 = (i >= s)       ? (ai / bm) : 0.0;
    const double k2 = (i + s < XLEN) ? (ci / bp) : 0.0;
    const double nb = bi - k1 * cm - k2 * ap;
    const double nd = di - k1 * dm - k2 * dp;
    const double na = -k1 * am;
    const double nc = -k2 * cp;
    __syncthreads();
    A[i] = na; B[i] = nb; C[i] = nc; D[i] = nd;
    __syncthreads();
  }

  out[g] = (float)(D[i] / B[i]);
}

extern "C" void kernel_launch(void* const* d_in, const int* in_sizes, int n_in,
                              void* d_out, int out_size, void* d_ws, size_t ws_size,
                              hipStream_t stream) {
  const float* x      = (const float*)d_in[0];
  const float* w_comp = (const float*)d_in[1];
  float* out = (float*)d_out;

  float* mu_ws  = (float*)d_ws;
  float* sig_ws = mu_ws + ROWS;

  gaus_fit_kernel<<<ROWS / 4, 256, 0, stream>>>(x, mu_ws, sig_ws);
  pcr_solve_kernel<<<BN, XLEN, 0, stream>>>(mu_ws, sig_ws, w_comp, out);
}

// Round 2
// 61.523 us; speedup vs baseline: 1.3947x; 1.3947x over previous
//
#include <hip/hip_runtime.h>
#include <hip/hip_bf16.h>
#include <math.h>

#define BN 32
#define XLEN 1024
#define COLS 512
#define ROWS (BN * XLEN)   // 32768
#define STAB 1e-15

// ---------------------------------------------------------------------------
// Kernel 1: softmax (f32) -> min-max normalize (f32) -> weighted Gaussian fit
// (f64), one wave (64 lanes) per row, 8 columns per lane, shuffle reductions.
// Custom table-based f64 log (input is a float in [0.001, 1.001]):
//   y = 2^e * m,  m in [1,2);  m = m_hi*(1+r), m_hi = 1+idx/128 (top 7
//   mantissa bits), r = (m - m_hi)/m_hi < 2^-7 computed exactly;
//   ln y = e*ln2 + ln(m_hi) + ln1p(r)   [deg-7 Taylor, |err| < 2e-18]
// Absolute error ~1e-15 vs lib log — far below the f32 noise floor of the
// upstream softmax/normalize pipeline.
// ---------------------------------------------------------------------------
__global__ __launch_bounds__(256) void gaus_fit_kernel(
    const float* __restrict__ x, float* __restrict__ mu_out,
    float* __restrict__ sig_out) {
  // [idx][0] = ln(1 + idx/128), [idx][1] = 1/(1 + idx/128), 16B-aligned pairs
  __shared__ double tab[128][2];
  if (threadIdx.x < 128) {
    const double mh = 1.0 + (double)threadIdx.x * (1.0 / 128.0);
    tab[threadIdx.x][0] = log(mh);   // one parallel lib-log per block
    tab[threadIdx.x][1] = 1.0 / mh;
  }
  __syncthreads();

  const int lane = threadIdx.x & 63;
  const int wid  = threadIdx.x >> 6;
  const int row  = blockIdx.x * 4 + wid;

  const float4* rp = (const float4*)(x + (size_t)row * COLS);
  float4 v0 = rp[lane];        // cols lane*4 .. lane*4+3
  float4 v1 = rp[lane + 64];   // cols 256+lane*4 .. 256+lane*4+3
  float xv[8] = {v0.x, v0.y, v0.z, v0.w, v1.x, v1.y, v1.z, v1.w};

  // row max (f32)
  float mx = xv[0];
#pragma unroll
  for (int k = 1; k < 8; ++k) mx = fmaxf(mx, xv[k]);
#pragma unroll
  for (int m = 32; m >= 1; m >>= 1) mx = fmaxf(mx, __shfl_xor(mx, m, 64));

  // exp and sum (f32)
  float e[8];
  float S = 0.0f;
#pragma unroll
  for (int k = 0; k < 8; ++k) {
    e[k] = expf(xv[k] - mx);
    S += e[k];
  }
#pragma unroll
  for (int m = 32; m >= 1; m >>= 1) S += __shfl_xor(S, m, 64);
  const float invS = 1.0f / S;   // wave-uniform, 1-ulp class vs per-elem div

  // p = e * invS; reduce min / max of p (f32)
  float p[8];
  float pmin = 3.0e38f, pmax = -3.0e38f;
#pragma unroll
  for (int k = 0; k < 8; ++k) {
    p[k] = e[k] * invS;
    pmin = fminf(pmin, p[k]);
    pmax = fmaxf(pmax, p[k]);
  }
#pragma unroll
  for (int m = 32; m >= 1; m >>= 1) {
    pmin = fminf(pmin, __shfl_xor(pmin, m, 64));
    pmax = fmaxf(pmax, __shfl_xor(pmax, m, 64));
  }
  const float invden = 1.0f / (pmax - pmin);

  // f64 weighted sums with custom log
  double s_y2 = 0.0, s_xy2 = 0.0, s_x2y2 = 0.0, s_x3y2 = 0.0, s_x4y2 = 0.0;
  double s_y2l = 0.0, s_xy2l = 0.0, s_x2y2l = 0.0;
#pragma unroll
  for (int k = 0; k < 8; ++k) {
    const int col = (k < 4) ? (lane * 4 + k) : (256 + lane * 4 + (k - 4));
    const float pn = (p[k] - pmin) * invden + 0.001f;   // in [0.001, 1.001]

    // --- custom f64 log of the float pn ---
    const unsigned bits = __float_as_uint(pn);
    const int      ex   = (int)(bits >> 23) - 127;
    const unsigned idx  = (bits >> 16) & 0x7Fu;
    const float    m    = __uint_as_float((bits & 0x007FFFFFu) | 0x3F800000u);
    const float    mh   = __uint_as_float(0x3F800000u | (idx << 16));
    const double   ln_mh = tab[idx][0];
    const double   inv_mh = tab[idx][1];
    const double   r = (double)(m - mh) * inv_mh;       // exact d * rounded inv
    double P = -0.125;                                  // deg-7 Taylor ln1p(r)/r
    P = fma(P, r,  1.0 / 7.0);
    P = fma(P, r, -1.0 / 6.0);
    P = fma(P, r,  0.2);
    P = fma(P, r, -0.25);
    P = fma(P, r,  1.0 / 3.0);
    P = fma(P, r, -0.5);
    P = fma(P, r,  1.0);
    const double lny = fma((double)ex, 0x1.62e42fefa39efp-1, ln_mh) + r * P;
    // --------------------------------------

    const double y  = (double)pn;
    const double y2 = y * y;
    const double y2l = y2 * lny;
    const double x1 = (double)col;
    const double x2 = x1 * x1;
    const double x3 = x2 * x1;
    const double x4 = x2 * x2;
    s_y2    += y2;
    s_xy2   += x1 * y2;
    s_x2y2  += x2 * y2;
    s_x3y2  += x3 * y2;
    s_x4y2  += x4 * y2;
    s_y2l   += y2l;
    s_xy2l  += x1 * y2l;
    s_x2y2l += x2 * y2l;
  }
#pragma unroll
  for (int m = 32; m >= 1; m >>= 1) {
    s_y2    += __shfl_xor(s_y2, m, 64);
    s_xy2   += __shfl_xor(s_xy2, m, 64);
    s_x2y2  += __shfl_xor(s_x2y2, m, 64);
    s_x3y2  += __shfl_xor(s_x3y2, m, 64);
    s_x4y2  += __shfl_xor(s_x4y2, m, 64);
    s_y2l   += __shfl_xor(s_y2l, m, 64);
    s_xy2l  += __shfl_xor(s_xy2l, m, 64);
    s_x2y2l += __shfl_xor(s_x2y2l, m, 64);
  }

  if (lane == 0) {
    const double A2 = s_x2y2 * s_x2y2;
    double b_num = A2 * s_xy2l - s_y2 * s_x4y2 * s_xy2l
                 + s_xy2 * s_x4y2 * s_y2l + s_y2 * s_x3y2 * s_x2y2l
                 - s_x2y2 * s_x3y2 * s_y2l - s_xy2 * s_x2y2 * s_x2y2l;
    double c_num = s_x2y2l * s_xy2 * s_xy2 - s_xy2l * s_xy2 * s_x2y2
                 - s_x3y2 * s_y2l * s_xy2 + s_y2l * A2
                 - s_y2 * s_x2y2l * s_x2y2 + s_y2 * s_x3y2 * s_xy2l;
    if (fabs(c_num) < STAB) {
      c_num = (c_num > 0.0) ? STAB : ((c_num < 0.0) ? -STAB : 0.0);
    }
    const double mu = -b_num / (2.0 * c_num);
    const double c_din = s_x4y2 * s_xy2 * s_xy2
                       - 2.0 * s_xy2 * s_x2y2 * s_x3y2 + s_x2y2 * A2
                       - s_y2 * s_x4y2 * s_x2y2 + s_y2 * s_x3y2 * s_x3y2;
    double sigma = -0.5 * c_din / c_num;
    if (sigma < 1.0) sigma = 1.0;  // NaN stays NaN, matching jnp.where
    mu_out[row]  = (float)mu;
    sig_out[row] = (float)sigma;
  }
}

// ---------------------------------------------------------------------------
// Kernel 2: per-batch tridiagonal solve via parallel cyclic reduction (f64).
// ---------------------------------------------------------------------------
__global__ __launch_bounds__(1024) void pcr_solve_kernel(
    const float* __restrict__ mu, const float* __restrict__ sigma,
    const float* __restrict__ w_comp, float* __restrict__ out) {
  __shared__ double A[XLEN], B[XLEN], C[XLEN], D[XLEN];
  const int i = threadIdx.x;
  const int g = blockIdx.x * XLEN + i;

  const float w = w_comp[0];
  const float offf  = -2.0f * w;
  const float mainw = (i == 0 || i == XLEN - 1) ? (2.0f * w) : (4.0f * w);
  const float sr = 1.0f / sigma[g];      // f32, matches reference
  const float bf = mainw + sr;           // f32 diag entry
  const float df = mu[g] * sr;           // f32 rhs

  A[i] = (i == 0) ? 0.0 : (double)offf;
  C[i] = (i == XLEN - 1) ? 0.0 : (double)offf;
  B[i] = (double)bf;
  D[i] = (double)df;
  __syncthreads();

  for (int s = 1; s < XLEN; s <<= 1) {
    const double ai = A[i], bi = B[i], ci = C[i], di = D[i];
    double am = 0.0, cm = 0.0, dm = 0.0, bm = 1.0;
    double ap = 0.0, cp = 0.0, dp = 0.0, bp = 1.0;
    if (i >= s)        { am = A[i - s]; bm = B[i - s]; cm = C[i - s]; dm = D[i - s]; }
    if (i + s < XLEN)  { ap = A[i + s]; bp = B[i + s]; cp = C[i + s]; dp = D[i + s]; }
    const double k1 = (i >= s)       ? (ai / bm) : 0.0;
    const double k2 = (i + s < XLEN) ? (ci / bp) : 0.0;
    const double nb = bi - k1 * cm - k2 * ap;
    const double nd = di - k1 * dm - k2 * dp;
    const double na = -k1 * am;
    const double nc = -k2 * cp;
    __syncthreads();
    A[i] = na; B[i] = nb; C[i] = nc; D[i] = nd;
    __syncthreads();
  }

  out[g] = (float)(D[i] / B[i]);
}

extern "C" void kernel_launch(void* const* d_in, const int* in_sizes, int n_in,
                              void* d_out, int out_size, void* d_ws, size_t ws_size,
                              hipStream_t stream) {
  const float* x      = (const float*)d_in[0];
  const float* w_comp = (const float*)d_in[1];
  float* out = (float*)d_out;

  float* mu_ws  = (float*)d_ws;
  float* sig_ws = mu_ws + ROWS;

  gaus_fit_kernel<<<ROWS / 4, 256, 0, stream>>>(x, mu_ws, sig_ws);
  pcr_solve_kernel<<<BN, XLEN, 0, stream>>>(mu_ws, sig_ws, w_comp, out);
}

// Round 4
// 41.699 us; speedup vs baseline: 2.0577x; 1.4754x over previous
//
#include <hip/hip_runtime.h>
#include <hip/hip_bf16.h>
#include <math.h>

#define BN 32
#define XLEN 1024
#define COLS 512
#define ROWS (BN * XLEN)   // 32768
#define STAB 1e-15

// ---------------------------------------------------------------------------
// Kernel 1: softmax (f32) -> min-max normalize (f32) -> weighted Gaussian fit
// (f64). 4 rows per wave: 16 lanes per row, 32 columns per lane.
// Reductions are 4-step __shfl_xor butterflies (m=1,2,4,8) that serve all
// 4 rows simultaneously; the closed-form fit formula runs once per wave in
// the 4 group-leader lanes.
// Custom table-based f64 log (input is a float in [0.001, 1.001]):
//   y = 2^e * m, m in [1,2); m = m_hi*(1+r), m_hi = 1+idx/128 (top 7 mantissa
//   bits), r = (m - m_hi)*inv_mh exact-diff * rounded-recip;
//   ln y = e*ln2 + ln(m_hi) + r*P(r)  [deg-6 ln1p, |err| ~ 2.5e-16]
// ---------------------------------------------------------------------------
__global__ __launch_bounds__(256) void gaus_fit_kernel(
    const float* __restrict__ x, float* __restrict__ mu_out,
    float* __restrict__ sig_out) {
  // [idx][0] = ln(1 + idx/128), [idx][1] = 1/(1 + idx/128)
  __shared__ double tab[128][2];
  if (threadIdx.x < 128) {
    const double mh = 1.0 + (double)threadIdx.x * (1.0 / 128.0);
    tab[threadIdx.x][0] = log(mh);   // one parallel lib-log per block
    tab[threadIdx.x][1] = 1.0 / mh;
  }
  __syncthreads();

  const int lane = threadIdx.x & 63;
  const int wid  = threadIdx.x >> 6;   // wave 0..3 in block
  const int sub  = lane & 15;          // lane within row-group
  const int row  = blockIdx.x * 16 + wid * 4 + (lane >> 4);

  // Each lane: 8 float4 loads; elem j covers cols 64*j + 4*sub + t, t=0..3.
  const float4* rp = (const float4*)(x + (size_t)row * COLS);
  float4 v[8];
#pragma unroll
  for (int j = 0; j < 8; ++j) v[j] = rp[16 * j + sub];

  // row max (f32) over this lane's 32 values, then 4-step butterfly
  float mx = v[0].x;
#pragma unroll
  for (int j = 0; j < 8; ++j) {
    mx = fmaxf(mx, fmaxf(fmaxf(v[j].x, v[j].y), fmaxf(v[j].z, v[j].w)));
  }
#pragma unroll
  for (int m = 8; m >= 1; m >>= 1) mx = fmaxf(mx, __shfl_xor(mx, m, 64));

  // exp; accumulate sum/min/max of e (min/max of p = scaled min/max of e,
  // identical results by monotone rounding — same class round 2 passed with)
  float e[32];
  float S = 0.0f, emin = 3.0e38f, emax = -3.0e38f;
#pragma unroll
  for (int j = 0; j < 8; ++j) {
    const float a0 = expf(v[j].x - mx), a1 = expf(v[j].y - mx);
    const float a2 = expf(v[j].z - mx), a3 = expf(v[j].w - mx);
    e[4 * j + 0] = a0; e[4 * j + 1] = a1; e[4 * j + 2] = a2; e[4 * j + 3] = a3;
    S += a0 + a1 + a2 + a3;
    emin = fminf(emin, fminf(fminf(a0, a1), fminf(a2, a3)));
    emax = fmaxf(emax, fmaxf(fmaxf(a0, a1), fmaxf(a2, a3)));
  }
#pragma unroll
  for (int m = 8; m >= 1; m >>= 1) {
    S    += __shfl_xor(S, m, 64);
    emin  = fminf(emin, __shfl_xor(emin, m, 64));
    emax  = fmaxf(emax, __shfl_xor(emax, m, 64));
  }
  const float invS   = 1.0f / S;
  const float pmin   = emin * invS;
  const float pmax   = emax * invS;
  const float invden = 1.0f / (pmax - pmin);

  // f64 weighted sums with custom log
  const double dsub = (double)(4 * sub);
  double s0 = 0.0, s1 = 0.0, s2 = 0.0, s3 = 0.0, s4 = 0.0;
  double t0 = 0.0, t1 = 0.0, t2 = 0.0;
#pragma unroll
  for (int j = 0; j < 8; ++j) {
#pragma unroll
    for (int t = 0; t < 4; ++t) {
      const float p  = e[4 * j + t] * invS;
      const float pn = (p - pmin) * invden + 0.001f;   // in [0.001, 1.001]

      // --- custom f64 log of the float pn ---
      const unsigned bits = __float_as_uint(pn);
      const int      ex   = (int)(bits >> 23) - 127;
      const unsigned idx  = (bits >> 16) & 0x7Fu;
      const float    m    = __uint_as_float((bits & 0x007FFFFFu) | 0x3F800000u);
      const float    mh   = __uint_as_float(0x3F800000u | (idx << 16));
      const double   ln_mh  = tab[idx][0];
      const double   inv_mh = tab[idx][1];
      const double   r = (double)(m - mh) * inv_mh;   // exact diff * recip
      double P = -1.0 / 6.0;                           // ln1p(r)/r, deg 5
      P = fma(P, r,  0.2);
      P = fma(P, r, -0.25);
      P = fma(P, r,  1.0 / 3.0);
      P = fma(P, r, -0.5);
      P = fma(P, r,  1.0);
      const double lny = fma((double)ex, 0x1.62e42fefa39efp-1, ln_mh) + r * P;
      // --------------------------------------

      const double y   = (double)pn;
      const double y2  = y * y;
      const double y2l = y2 * lny;
      const double x1  = dsub + (double)(64 * j + t);  // col as f64, 1 add
      const double x2  = x1 * x1;
      const double x3  = x2 * x1;
      const double x4  = x2 * x2;
      s0 += y2;
      s1 = fma(x1, y2, s1);
      s2 = fma(x2, y2, s2);
      s3 = fma(x3, y2, s3);
      s4 = fma(x4, y2, s4);
      t0 += y2l;
      t1 = fma(x1, y2l, t1);
      t2 = fma(x2, y2l, t2);
    }
  }
#pragma unroll
  for (int m = 8; m >= 1; m >>= 1) {
    s0 += __shfl_xor(s0, m, 64);
    s1 += __shfl_xor(s1, m, 64);
    s2 += __shfl_xor(s2, m, 64);
    s3 += __shfl_xor(s3, m, 64);
    s4 += __shfl_xor(s4, m, 64);
    t0 += __shfl_xor(t0, m, 64);
    t1 += __shfl_xor(t1, m, 64);
    t2 += __shfl_xor(t2, m, 64);
  }

  if (sub == 0) {   // lanes 0,16,32,48 — one per row
    const double s_y2 = s0, s_xy2 = s1, s_x2y2 = s2, s_x3y2 = s3, s_x4y2 = s4;
    const double s_y2l = t0, s_xy2l = t1, s_x2y2l = t2;
    const double A2 = s_x2y2 * s_x2y2;
    double b_num = A2 * s_xy2l - s_y2 * s_x4y2 * s_xy2l
                 + s_xy2 * s_x4y2 * s_y2l + s_y2 * s_x3y2 * s_x2y2l
                 - s_x2y2 * s_x3y2 * s_y2l - s_xy2 * s_x2y2 * s_x2y2l;
    double c_num = s_x2y2l * s_xy2 * s_xy2 - s_xy2l * s_xy2 * s_x2y2
                 - s_x3y2 * s_y2l * s_xy2 + s_y2l * A2
                 - s_y2 * s_x2y2l * s_x2y2 + s_y2 * s_x3y2 * s_xy2l;
    if (fabs(c_num) < STAB) {
      c_num = (c_num > 0.0) ? STAB : ((c_num < 0.0) ? -STAB : 0.0);
    }
    const double mu = -b_num / (2.0 * c_num);
    const double c_din = s_x4y2 * s_xy2 * s_xy2
                       - 2.0 * s_xy2 * s_x2y2 * s_x3y2 + s_x2y2 * A2
                       - s_y2 * s_x4y2 * s_x2y2 + s_y2 * s_x3y2 * s_x3y2;
    double sigma = -0.5 * c_din / c_num;
    if (sigma < 1.0) sigma = 1.0;  // NaN stays NaN, matching jnp.where
    mu_out[row]  = (float)mu;
    sig_out[row] = (float)sigma;
  }
}

// ---------------------------------------------------------------------------
// Kernel 2: per-batch tridiagonal solve via parallel cyclic reduction (f64).
// ---------------------------------------------------------------------------
__global__ __launch_bounds__(1024) void pcr_solve_kernel(
    const float* __restrict__ mu, const float* __restrict__ sigma,
    const float* __restrict__ w_comp, float* __restrict__ out) {
  __shared__ double A[XLEN], B[XLEN], C[XLEN], D[XLEN];
  const int i = threadIdx.x;
  const int g = blockIdx.x * XLEN + i;

  const float w = w_comp[0];
  const float offf  = -2.0f * w;
  const float mainw = (i == 0 || i == XLEN - 1) ? (2.0f * w) : (4.0f * w);
  const float sr = 1.0f / sigma[g];      // f32, matches reference
  const float bf = mainw + sr;           // f32 diag entry
  const float df = mu[g] * sr;           // f32 rhs

  A[i] = (i == 0) ? 0.0 : (double)offf;
  C[i] = (i == XLEN - 1) ? 0.0 : (double)offf;
  B[i] = (double)bf;
  D[i] = (double)df;
  __syncthreads();

  for (int s = 1; s < XLEN; s <<= 1) {
    const double ai = A[i], bi = B[i], ci = C[i], di = D[i];
    double am = 0.0, cm = 0.0, dm = 0.0, bm = 1.0;
    double ap = 0.0, cp = 0.0, dp = 0.0, bp = 1.0;
    if (i >= s)        { am = A[i - s]; bm = B[i - s]; cm = C[i - s]; dm = D[i - s]; }
    if (i + s < XLEN)  { ap = A[i + s]; bp = B[i + s]; cp = C[i + s]; dp = D[i + s]; }
    const double k1 = (i >= s)       ? (ai / bm) : 0.0;
    const double k2 = (i + s < XLEN) ? (ci / bp) : 0.0;
    const double nb = bi - k1 * cm - k2 * ap;
    const double nd = di - k1 * dm - k2 * dp;
    const double na = -k1 * am;
    const double nc = -k2 * cp;
    __syncthreads();
    A[i] = na; B[i] = nb; C[i] = nc; D[i] = nd;
    __syncthreads();
  }

  out[g] = (float)(D[i] / B[i]);
}

extern "C" void kernel_launch(void* const* d_in, const int* in_sizes, int n_in,
                              void* d_out, int out_size, void* d_ws, size_t ws_size,
                              hipStream_t stream) {
  const float* x      = (const float*)d_in[0];
  const float* w_comp = (const float*)d_in[1];
  float* out = (float*)d_out;

  float* mu_ws  = (float*)d_ws;
  float* sig_ws = mu_ws + ROWS;

  gaus_fit_kernel<<<ROWS / 16, 256, 0, stream>>>(x, mu_ws, sig_ws);
  pcr_solve_kernel<<<BN, XLEN, 0, stream>>>(mu_ws, sig_ws, w_comp, out);
}

// Round 5
// 38.393 us; speedup vs baseline: 2.2349x; 1.0861x over previous
//
#include <hip/hip_runtime.h>
#include <hip/hip_bf16.h>
#include <math.h>

#define BN 32
#define XLEN 1024
#define COLS 512
#define ROWS (BN * XLEN)   // 32768
#define STAB 1e-15

// ---------------------------------------------------------------------------
// Kernel 1: softmax (f32) -> min-max normalize (f32) -> weighted Gaussian fit
// (f64). 4 rows per wave: 16 lanes per row, 32 columns per lane; 2 waves per
// 128-thread block (8 rows/block, grid 4096 = 16 blocks/CU for packing slack).
// exp is recomputed in pass B (__expf = 2 instrs) so no e[32] array stays
// live -> ~60 VGPR leaves room for the compiler to interleave log chains.
// Hybrid log of float pn in [0.001, 1.001]:
//   pn = 2^e * m, m = m_hi*(1+r), m_hi = 1+idx/128 (top 7 mantissa bits)
//   lny = fma(e, ln2, lntab[idx])  [f64]  +  (double)(r*P(r))  [f32 tail]
//   r = (m-m_hi)*rcp(m_hi) in f32 (r < 2^-7), deg-3 Horner.
//   |err| ~ 2e-9 absolute, ~3.5 orders below the accepted f32 noise floor.
// ---------------------------------------------------------------------------
__global__ __launch_bounds__(128, 6) void gaus_fit_kernel(
    const float* __restrict__ x, float* __restrict__ mu_out,
    float* __restrict__ sig_out) {
  __shared__ double lntab[128];
  lntab[threadIdx.x] = log(1.0 + (double)threadIdx.x * (1.0 / 128.0));
  __syncthreads();

  const int lane = threadIdx.x & 63;
  const int wid  = threadIdx.x >> 6;   // wave 0..1 in block
  const int sub  = lane & 15;          // lane within row-group
  const int row  = blockIdx.x * 8 + wid * 4 + (lane >> 4);

  // Each lane: 8 float4 loads; elem (j,t) covers col 64*j + 4*sub + t.
  const float4* rp = (const float4*)(x + (size_t)row * COLS);
  float4 v[8];
#pragma unroll
  for (int j = 0; j < 8; ++j) v[j] = rp[16 * j + sub];

  // row max (f32), 4-step butterfly serves all 4 rows
  float mx = v[0].x;
#pragma unroll
  for (int j = 0; j < 8; ++j) {
    mx = fmaxf(mx, fmaxf(fmaxf(v[j].x, v[j].y), fmaxf(v[j].z, v[j].w)));
  }
#pragma unroll
  for (int m = 8; m >= 1; m >>= 1) mx = fmaxf(mx, __shfl_xor(mx, m, 64));

  // pass A: sum / min / max of e (min/max of p = scaled min/max of e —
  // monotone-rounding equivalent, same class rounds 2/4 passed with)
  float S = 0.0f, emin = 3.0e38f, emax = -3.0e38f;
#pragma unroll
  for (int j = 0; j < 8; ++j) {
    const float a0 = __expf(v[j].x - mx), a1 = __expf(v[j].y - mx);
    const float a2 = __expf(v[j].z - mx), a3 = __expf(v[j].w - mx);
    S += a0 + a1 + a2 + a3;
    emin = fminf(emin, fminf(fminf(a0, a1), fminf(a2, a3)));
    emax = fmaxf(emax, fmaxf(fmaxf(a0, a1), fmaxf(a2, a3)));
  }
#pragma unroll
  for (int m = 8; m >= 1; m >>= 1) {
    S    += __shfl_xor(S, m, 64);
    emin  = fminf(emin, __shfl_xor(emin, m, 64));
    emax  = fmaxf(emax, __shfl_xor(emax, m, 64));
  }
  const float invS   = 1.0f / S;
  const float pmin   = emin * invS;
  const float pmax   = emax * invS;
  const float invden = 1.0f / (pmax - pmin);

  // pass B: f64 weighted sums with hybrid log (exp recomputed on the fly)
  const double dsub = (double)(4 * sub);
  double s0 = 0.0, s1 = 0.0, s2 = 0.0, s3 = 0.0, s4 = 0.0;
  double t0 = 0.0, t1 = 0.0, t2 = 0.0;
#pragma unroll
  for (int j = 0; j < 8; ++j) {
    const float a[4] = {v[j].x, v[j].y, v[j].z, v[j].w};
#pragma unroll
    for (int t = 0; t < 4; ++t) {
      const float e  = __expf(a[t] - mx);
      const float p  = e * invS;
      const float pn = (p - pmin) * invden + 0.001f;   // in [0.001, 1.001]

      // --- hybrid f64/f32 log of the float pn ---
      const unsigned bits = __float_as_uint(pn);
      const int      exd  = (int)(bits >> 23) - 127;
      const unsigned idx  = (bits >> 16) & 0x7Fu;
      const float    m    = __uint_as_float((bits & 0x007FFFFFu) | 0x3F800000u);
      const float    mh   = __uint_as_float(0x3F800000u | (idx << 16));
      const float    rf   = (m - mh) * __builtin_amdgcn_rcpf(mh);  // |rf| < 2^-7
      float P = fmaf(-0.25f, rf, 0.3333333333f);   // ln1p(rf)/rf, deg 3
      P = fmaf(P, rf, -0.5f);
      P = fmaf(P, rf, 1.0f);
      const double lny =
          fma((double)exd, 0x1.62e42fefa39efp-1, lntab[idx]) + (double)(rf * P);
      // ------------------------------------------

      const double y   = (double)pn;
      const double y2  = y * y;
      const double y2l = y2 * lny;
      const double x1  = dsub + (double)(64 * j + t);
      const double x2  = x1 * x1;
      const double x3  = x2 * x1;
      const double x4  = x2 * x2;
      s0 += y2;
      s1 = fma(x1, y2, s1);
      s2 = fma(x2, y2, s2);
      s3 = fma(x3, y2, s3);
      s4 = fma(x4, y2, s4);
      t0 += y2l;
      t1 = fma(x1, y2l, t1);
      t2 = fma(x2, y2l, t2);
    }
  }
#pragma unroll
  for (int m = 8; m >= 1; m >>= 1) {
    s0 += __shfl_xor(s0, m, 64);
    s1 += __shfl_xor(s1, m, 64);
    s2 += __shfl_xor(s2, m, 64);
    s3 += __shfl_xor(s3, m, 64);
    s4 += __shfl_xor(s4, m, 64);
    t0 += __shfl_xor(t0, m, 64);
    t1 += __shfl_xor(t1, m, 64);
    t2 += __shfl_xor(t2, m, 64);
  }

  if (sub == 0) {   // lanes 0,16,32,48 — one per row
    const double s_y2 = s0, s_xy2 = s1, s_x2y2 = s2, s_x3y2 = s3, s_x4y2 = s4;
    const double s_y2l = t0, s_xy2l = t1, s_x2y2l = t2;
    const double A2 = s_x2y2 * s_x2y2;
    double b_num = A2 * s_xy2l - s_y2 * s_x4y2 * s_xy2l
                 + s_xy2 * s_x4y2 * s_y2l + s_y2 * s_x3y2 * s_x2y2l
                 - s_x2y2 * s_x3y2 * s_y2l - s_xy2 * s_x2y2 * s_x2y2l;
    double c_num = s_x2y2l * s_xy2 * s_xy2 - s_xy2l * s_xy2 * s_x2y2
                 - s_x3y2 * s_y2l * s_xy2 + s_y2l * A2
                 - s_y2 * s_x2y2l * s_x2y2 + s_y2 * s_x3y2 * s_xy2l;
    if (fabs(c_num) < STAB) {
      c_num = (c_num > 0.0) ? STAB : ((c_num < 0.0) ? -STAB : 0.0);
    }
    const double mu = -b_num / (2.0 * c_num);
    const double c_din = s_x4y2 * s_xy2 * s_xy2
                       - 2.0 * s_xy2 * s_x2y2 * s_x3y2 + s_x2y2 * A2
                       - s_y2 * s_x4y2 * s_x2y2 + s_y2 * s_x3y2 * s_x3y2;
    double sigma = -0.5 * c_din / c_num;
    if (sigma < 1.0) sigma = 1.0;  // NaN stays NaN, matching jnp.where
    mu_out[row]  = (float)mu;
    sig_out[row] = (float)sigma;
  }
}

// ---------------------------------------------------------------------------
// Kernel 2: per-batch tridiagonal solve via parallel cyclic reduction (f64).
// One reciprocal per thread per step shared through LDS (R[i] = 1/B[i])
// replaces two divides; final divide becomes a multiply.
// ---------------------------------------------------------------------------
__global__ __launch_bounds__(1024) void pcr_solve_kernel(
    const float* __restrict__ mu, const float* __restrict__ sigma,
    const float* __restrict__ w_comp, float* __restrict__ out) {
  __shared__ double A[XLEN], B[XLEN], C[XLEN], D[XLEN], R[XLEN];
  const int i = threadIdx.x;
  const int g = blockIdx.x * XLEN + i;

  const float w = w_comp[0];
  const float offf  = -2.0f * w;
  const float mainw = (i == 0 || i == XLEN - 1) ? (2.0f * w) : (4.0f * w);
  const float sr = 1.0f / sigma[g];      // f32, matches reference
  const float bf = mainw + sr;           // f32 diag entry
  const float df = mu[g] * sr;           // f32 rhs

  A[i] = (i == 0) ? 0.0 : (double)offf;
  C[i] = (i == XLEN - 1) ? 0.0 : (double)offf;
  B[i] = (double)bf;
  D[i] = (double)df;
  R[i] = 1.0 / (double)bf;
  __syncthreads();

  for (int s = 1; s < XLEN; s <<= 1) {
    const double ai = A[i], bi = B[i], ci = C[i], di = D[i];
    double am = 0.0, cm = 0.0, dm = 0.0, rm = 0.0;
    double ap = 0.0, cp = 0.0, dp = 0.0, rp = 0.0;
    if (i >= s)        { am = A[i - s]; cm = C[i - s]; dm = D[i - s]; rm = R[i - s]; }
    if (i + s < XLEN)  { ap = A[i + s]; cp = C[i + s]; dp = D[i + s]; rp = R[i + s]; }
    const double k1 = ai * rm;   // rm/rp are 0 when guarded out
    const double k2 = ci * rp;
    const double nb = bi - k1 * cm - k2 * ap;
    const double nd = di - k1 * dm - k2 * dp;
    const double na = -k1 * am;
    const double nc = -k2 * cp;
    const double nr = 1.0 / nb;
    __syncthreads();
    A[i] = na; B[i] = nb; C[i] = nc; D[i] = nd; R[i] = nr;
    __syncthreads();
  }

  out[g] = (float)(D[i] * R[i]);
}

extern "C" void kernel_launch(void* const* d_in, const int* in_sizes, int n_in,
                              void* d_out, int out_size, void* d_ws, size_t ws_size,
                              hipStream_t stream) {
  const float* x      = (const float*)d_in[0];
  const float* w_comp = (const float*)d_in[1];
  float* out = (float*)d_out;

  float* mu_ws  = (float*)d_ws;
  float* sig_ws = mu_ws + ROWS;

  gaus_fit_kernel<<<ROWS / 8, 128, 0, stream>>>(x, mu_ws, sig_ws);
  pcr_solve_kernel<<<BN, XLEN, 0, stream>>>(mu_ws, sig_ws, w_comp, out);
}

// Round 6
// 36.522 us; speedup vs baseline: 2.3494x; 1.0512x over previous
//
#include <hip/hip_runtime.h>
#include <hip/hip_bf16.h>
#include <math.h>

#define BN 32
#define XLEN 1024
#define COLS 512
#define ROWS (BN * XLEN)   // 32768
#define STAB 1e-15

// ---------------------------------------------------------------------------
// Kernel 1: softmax (f32) -> min-max normalize (f32) -> weighted Gaussian fit.
// 4 rows per wave: 16 lanes per row, 32 columns per lane; 2 waves per
// 128-thread block.
// Fully-f32 per-element pipeline (error class == the inherent 1-ulp f32
// noise of pn that the reference pipeline itself carries):
//   ln(pn): pn = 2^e * m, m in [1,2);  z = (m-1)/(m+1) in [0,1/3]
//           ln m = z*(2 + (2/3)z^2 + ... + (2/13)z^12)   [abs err < 1e-7]
//           ln pn = fma(e, ln2, ln m)                     -- no table, no LDS
//   moments: x_hat = col/512 in [0,1) -> all 8 weighted sums are O(32)/lane,
//           accumulated in f32, converted to f64 for the 16-lane butterfly.
//   Unscaling by 512^k (exact f64 powers of 2) restores the original-unit
//   sums; the closed-form formula + STAB/sigma clamps run in f64 verbatim.
// ---------------------------------------------------------------------------
__global__ __launch_bounds__(128, 5) void gaus_fit_kernel(
    const float* __restrict__ x, float* __restrict__ mu_out,
    float* __restrict__ sig_out) {
  const int lane = threadIdx.x & 63;
  const int wid  = threadIdx.x >> 6;   // wave 0..1 in block
  const int sub  = lane & 15;          // lane within row-group
  const int row  = blockIdx.x * 8 + wid * 4 + (lane >> 4);

  // Each lane: 8 float4 loads; elem (j,t) covers col 64*j + 4*sub + t.
  const float4* rp = (const float4*)(x + (size_t)row * COLS);
  float4 v[8];
#pragma unroll
  for (int j = 0; j < 8; ++j) v[j] = rp[16 * j + sub];

  // row max (f32), 4-step butterfly serves all 4 rows
  float mx = v[0].x;
#pragma unroll
  for (int j = 0; j < 8; ++j) {
    mx = fmaxf(mx, fmaxf(fmaxf(v[j].x, v[j].y), fmaxf(v[j].z, v[j].w)));
  }
#pragma unroll
  for (int m = 8; m >= 1; m >>= 1) mx = fmaxf(mx, __shfl_xor(mx, m, 64));

  // pass A: e[] = exp(x - mx); sum / min / max of e (min/max of p = scaled
  // min/max of e — monotone-rounding equivalent, accepted since round 2)
  float e[32];
  float S = 0.0f, emin = 3.0e38f, emax = -3.0e38f;
#pragma unroll
  for (int j = 0; j < 8; ++j) {
    const float a0 = __expf(v[j].x - mx), a1 = __expf(v[j].y - mx);
    const float a2 = __expf(v[j].z - mx), a3 = __expf(v[j].w - mx);
    e[4 * j + 0] = a0; e[4 * j + 1] = a1; e[4 * j + 2] = a2; e[4 * j + 3] = a3;
    S += a0 + a1 + a2 + a3;
    emin = fminf(emin, fminf(fminf(a0, a1), fminf(a2, a3)));
    emax = fmaxf(emax, fmaxf(fmaxf(a0, a1), fmaxf(a2, a3)));
  }
#pragma unroll
  for (int m = 8; m >= 1; m >>= 1) {
    S    += __shfl_xor(S, m, 64);
    emin  = fminf(emin, __shfl_xor(emin, m, 64));
    emax  = fmaxf(emax, __shfl_xor(emax, m, 64));
  }
  const float invS   = 1.0f / S;
  const float pmin   = emin * invS;
  const float pmax   = emax * invS;
  const float invden = 1.0f / (pmax - pmin);

  // pass B: all-f32 weighted sums with scaled x_hat = col/512
  const float dsub_s = (float)(4 * sub) * (1.0f / 512.0f);
  float s0 = 0.0f, s1 = 0.0f, s2 = 0.0f, s3 = 0.0f, s4 = 0.0f;
  float t0 = 0.0f, t1 = 0.0f, t2 = 0.0f;
#pragma unroll
  for (int j = 0; j < 8; ++j) {
#pragma unroll
    for (int t = 0; t < 4; ++t) {
      const float p  = e[4 * j + t] * invS;
      const float pn = (p - pmin) * invden + 0.001f;   // in [0.001, 1.001]

      // --- table-free f32 log of pn ---
      const unsigned bits = __float_as_uint(pn);
      const float    exdf = (float)((int)(bits >> 23) - 127);
      const float    m    = __uint_as_float((bits & 0x007FFFFFu) | 0x3F800000u);
      const float    z    = (m - 1.0f) * __builtin_amdgcn_rcpf(m + 1.0f);
      const float    u    = z * z;
      float P = fmaf(2.0f / 13.0f, u, 2.0f / 11.0f);   // 2*atanh(z)/z
      P = fmaf(P, u, 2.0f / 9.0f);
      P = fmaf(P, u, 2.0f / 7.0f);
      P = fmaf(P, u, 2.0f / 5.0f);
      P = fmaf(P, u, 2.0f / 3.0f);
      P = fmaf(P, u, 2.0f);
      const float lny = fmaf(exdf, 0.69314718056f, z * P);
      // --------------------------------

      const float y2  = pn * pn;
      const float y2l = y2 * lny;
      const float xh  = dsub_s + (float)(64 * j + t) * (1.0f / 512.0f);
      const float x2  = xh * xh;     // exact: xh has 9 significant bits
      const float x3  = x2 * xh;
      const float x4  = x2 * x2;
      s0 += y2;
      s1 = fmaf(xh, y2, s1);
      s2 = fmaf(x2, y2, s2);
      s3 = fmaf(x3, y2, s3);
      s4 = fmaf(x4, y2, s4);
      t0 += y2l;
      t1 = fmaf(xh, y2l, t1);
      t2 = fmaf(x2, y2l, t2);
    }
  }

  // convert lane sums to f64, 4-step f64 butterfly over the 16-lane groups
  double d0 = (double)s0, d1 = (double)s1, d2 = (double)s2, d3 = (double)s3;
  double d4 = (double)s4, e0 = (double)t0, e1 = (double)t1, e2 = (double)t2;
#pragma unroll
  for (int m = 8; m >= 1; m >>= 1) {
    d0 += __shfl_xor(d0, m, 64);
    d1 += __shfl_xor(d1, m, 64);
    d2 += __shfl_xor(d2, m, 64);
    d3 += __shfl_xor(d3, m, 64);
    d4 += __shfl_xor(d4, m, 64);
    e0 += __shfl_xor(e0, m, 64);
    e1 += __shfl_xor(e1, m, 64);
    e2 += __shfl_xor(e2, m, 64);
  }

  if (sub == 0) {   // lanes 0,16,32,48 — one per row
    // unscale: multiply by exact powers of 512 (exact f64 ops)
    const double s_y2    = d0;
    const double s_xy2   = d1 * 512.0;
    const double s_x2y2  = d2 * 262144.0;            // 512^2
    const double s_x3y2  = d3 * 134217728.0;         // 512^3
    const double s_x4y2  = d4 * 68719476736.0;       // 512^4
    const double s_y2l   = e0;
    const double s_xy2l  = e1 * 512.0;
    const double s_x2y2l = e2 * 262144.0;
    const double A2 = s_x2y2 * s_x2y2;
    double b_num = A2 * s_xy2l - s_y2 * s_x4y2 * s_xy2l
                 + s_xy2 * s_x4y2 * s_y2l + s_y2 * s_x3y2 * s_x2y2l
                 - s_x2y2 * s_x3y2 * s_y2l - s_xy2 * s_x2y2 * s_x2y2l;
    double c_num = s_x2y2l * s_xy2 * s_xy2 - s_xy2l * s_xy2 * s_x2y2
                 - s_x3y2 * s_y2l * s_xy2 + s_y2l * A2
                 - s_y2 * s_x2y2l * s_x2y2 + s_y2 * s_x3y2 * s_xy2l;
    if (fabs(c_num) < STAB) {
      c_num = (c_num > 0.0) ? STAB : ((c_num < 0.0) ? -STAB : 0.0);
    }
    const double mu = -b_num / (2.0 * c_num);
    const double c_din = s_x4y2 * s_xy2 * s_xy2
                       - 2.0 * s_xy2 * s_x2y2 * s_x3y2 + s_x2y2 * A2
                       - s_y2 * s_x4y2 * s_x2y2 + s_y2 * s_x3y2 * s_x3y2;
    double sigma = -0.5 * c_din / c_num;
    if (sigma < 1.0) sigma = 1.0;  // NaN stays NaN, matching jnp.where
    mu_out[row]  = (float)mu;
    sig_out[row] = (float)sigma;
  }
}

// ---------------------------------------------------------------------------
// Kernel 2: per-batch tridiagonal solve via parallel cyclic reduction (f64).
// Ping-pong buffers -> ONE barrier per step; shared reciprocal R = 1/B
// replaces two divides per step; final divide becomes a multiply.
// ---------------------------------------------------------------------------
__global__ __launch_bounds__(1024) void pcr_solve_kernel(
    const float* __restrict__ mu, const float* __restrict__ sigma,
    const float* __restrict__ w_comp, float* __restrict__ out) {
  __shared__ double A[2][XLEN], B[2][XLEN], C[2][XLEN], D[2][XLEN], R[2][XLEN];
  const int i = threadIdx.x;
  const int g = blockIdx.x * XLEN + i;

  const float w = w_comp[0];
  const float offf  = -2.0f * w;
  const float mainw = (i == 0 || i == XLEN - 1) ? (2.0f * w) : (4.0f * w);
  const float sr = 1.0f / sigma[g];      // f32, matches reference
  const float bf = mainw + sr;           // f32 diag entry
  const float df = mu[g] * sr;           // f32 rhs

  A[0][i] = (i == 0) ? 0.0 : (double)offf;
  C[0][i] = (i == XLEN - 1) ? 0.0 : (double)offf;
  B[0][i] = (double)bf;
  D[0][i] = (double)df;
  R[0][i] = 1.0 / (double)bf;
  __syncthreads();

  int cur = 0;
  for (int s = 1; s < XLEN; s <<= 1) {
    const double ai = A[cur][i], bi = B[cur][i], ci = C[cur][i], di = D[cur][i];
    double am = 0.0, cm = 0.0, dm = 0.0, rm = 0.0;
    double ap = 0.0, cp = 0.0, dp = 0.0, rp = 0.0;
    if (i >= s) {
      am = A[cur][i - s]; cm = C[cur][i - s]; dm = D[cur][i - s]; rm = R[cur][i - s];
    }
    if (i + s < XLEN) {
      ap = A[cur][i + s]; cp = C[cur][i + s]; dp = D[cur][i + s]; rp = R[cur][i + s];
    }
    const double k1 = ai * rm;   // rm/rp are 0 when guarded out
    const double k2 = ci * rp;
    const double nb = bi - k1 * cm - k2 * ap;
    const double nd = di - k1 * dm - k2 * dp;
    const int nxt = cur ^ 1;
    A[nxt][i] = -k1 * am;
    C[nxt][i] = -k2 * cp;
    B[nxt][i] = nb;
    D[nxt][i] = nd;
    R[nxt][i] = 1.0 / nb;
    __syncthreads();
    cur = nxt;
  }

  out[g] = (float)(D[cur][i] * R[cur][i]);
}

extern "C" void kernel_launch(void* const* d_in, const int* in_sizes, int n_in,
                              void* d_out, int out_size, void* d_ws, size_t ws_size,
                              hipStream_t stream) {
  const float* x      = (const float*)d_in[0];
  const float* w_comp = (const float*)d_in[1];
  float* out = (float*)d_out;

  float* mu_ws  = (float*)d_ws;
  float* sig_ws = mu_ws + ROWS;

  gaus_fit_kernel<<<ROWS / 8, 128, 0, stream>>>(x, mu_ws, sig_ws);
  pcr_solve_kernel<<<BN, XLEN, 0, stream>>>(mu_ws, sig_ws, w_comp, out);
}

// Round 9
// 36.240 us; speedup vs baseline: 2.3677x; 1.0078x over previous
//
#include <hip/hip_runtime.h>
#include <hip/hip_bf16.h>
#include <math.h>

#define BN 32
#define XLEN 1024
#define COLS 512
#define ROWS (BN * XLEN)   // 32768
#define STAB 1e-15

// ---------------------------------------------------------------------------
// Kernel 1: softmax (f32) -> min-max normalize (f32) -> weighted Gaussian fit.
// 4 rows per wave: 16 lanes per row, 32 columns per lane; 4 waves per
// 256-thread block (16 rows/block, grid 2048 = 8 blocks/CU).
// NO e[] array: exp is recomputed in pass B (bit-identical to storing it),
// keeping the live set ~60-80 VGPR so nothing spills to scratch.
// Fully-f32 per-element pipeline (error class == the inherent 1-ulp f32
// noise of pn that the reference pipeline itself carries):
//   ln(pn): pn = 2^e * m, m in [1,2);  z = (m-1)/(m+1) in [0,1/3]
//           ln m = z*(2 + (2/3)z^2 + ... + (2/13)z^12)   [abs err < 1e-7]
//           ln pn = fma(e, ln2, ln m)                     -- no table, no LDS
//   moments: x_hat = col/512 in [0,1) -> all 8 weighted sums are O(32)/lane,
//           accumulated in f32, converted to f64 for the 16-lane butterfly.
//   Unscaling by 512^k (exact f64 powers of 2) restores original-unit sums;
//   the closed-form formula + STAB/sigma clamps run in f64 verbatim.
// ---------------------------------------------------------------------------
__global__ __launch_bounds__(256) void gaus_fit_kernel(
    const float* __restrict__ x, float* __restrict__ mu_out,
    float* __restrict__ sig_out) {
  const int lane = threadIdx.x & 63;
  const int wid  = threadIdx.x >> 6;   // wave 0..3 in block
  const int sub  = lane & 15;          // lane within row-group
  const int row  = blockIdx.x * 16 + wid * 4 + (lane >> 4);

  // Each lane: 8 float4 loads; elem (j,t) covers col 64*j + 4*sub + t.
  const float4* rp = (const float4*)(x + (size_t)row * COLS);
  float4 v[8];
#pragma unroll
  for (int j = 0; j < 8; ++j) v[j] = rp[16 * j + sub];

  // row max (f32), 4-step butterfly serves all 4 rows
  float mx = v[0].x;
#pragma unroll
  for (int j = 0; j < 8; ++j) {
    mx = fmaxf(mx, fmaxf(fmaxf(v[j].x, v[j].y), fmaxf(v[j].z, v[j].w)));
  }
#pragma unroll
  for (int m = 8; m >= 1; m >>= 1) mx = fmaxf(mx, __shfl_xor(mx, m, 64));

  // pass A: sum / min / max of e = exp(x - mx), nothing stored
  float S = 0.0f, emin = 3.0e38f, emax = -3.0e38f;
#pragma unroll
  for (int j = 0; j < 8; ++j) {
    const float a0 = __expf(v[j].x - mx), a1 = __expf(v[j].y - mx);
    const float a2 = __expf(v[j].z - mx), a3 = __expf(v[j].w - mx);
    S += a0 + a1 + a2 + a3;
    emin = fminf(emin, fminf(fminf(a0, a1), fminf(a2, a3)));
    emax = fmaxf(emax, fmaxf(fmaxf(a0, a1), fmaxf(a2, a3)));
  }
#pragma unroll
  for (int m = 8; m >= 1; m >>= 1) {
    S    += __shfl_xor(S, m, 64);
    emin  = fminf(emin, __shfl_xor(emin, m, 64));
    emax  = fmaxf(emax, __shfl_xor(emax, m, 64));
  }
  const float invS   = 1.0f / S;
  const float pmin   = emin * invS;
  const float pmax   = emax * invS;
  const float invden = 1.0f / (pmax - pmin);

  // pass B: all-f32 weighted sums; exp recomputed (bit-identical to pass A)
  const float dsub_s = (float)(4 * sub) * (1.0f / 512.0f);
  float s0 = 0.0f, s1 = 0.0f, s2 = 0.0f, s3 = 0.0f, s4 = 0.0f;
  float t0 = 0.0f, t1 = 0.0f, t2 = 0.0f;

#define GF_ELEM(j, t, comp)                                                   \
  {                                                                           \
    const float e  = __expf((comp) - mx);                                     \
    const float p  = e * invS;                                                \
    const float pn = (p - pmin) * invden + 0.001f;                            \
    const unsigned bits = __float_as_uint(pn);                                \
    const float    exdf = (float)((int)(bits >> 23) - 127);                   \
    const float    mm   = __uint_as_float((bits & 0x007FFFFFu) | 0x3F800000u);\
    const float    z    = (mm - 1.0f) * __builtin_amdgcn_rcpf(mm + 1.0f);     \
    const float    u    = z * z;                                              \
    float P = fmaf(2.0f / 13.0f, u, 2.0f / 11.0f);                            \
    P = fmaf(P, u, 2.0f / 9.0f);                                              \
    P = fmaf(P, u, 2.0f / 7.0f);                                              \
    P = fmaf(P, u, 2.0f / 5.0f);                                              \
    P = fmaf(P, u, 2.0f / 3.0f);                                              \
    P = fmaf(P, u, 2.0f);                                                     \
    const float lny = fmaf(exdf, 0.69314718056f, z * P);                      \
    const float y2  = pn * pn;                                                \
    const float y2l = y2 * lny;                                               \
    const float xh  = dsub_s + (float)(64 * (j) + (t)) * (1.0f / 512.0f);     \
    const float x2  = xh * xh;                                                \
    const float x3  = x2 * xh;                                                \
    const float x4  = x2 * x2;                                                \
    s0 += y2;                                                                 \
    s1 = fmaf(xh, y2, s1);                                                    \
    s2 = fmaf(x2, y2, s2);                                                    \
    s3 = fmaf(x3, y2, s3);                                                    \
    s4 = fmaf(x4, y2, s4);                                                    \
    t0 += y2l;                                                                \
    t1 = fmaf(xh, y2l, t1);                                                   \
    t2 = fmaf(x2, y2l, t2);                                                   \
  }

#pragma unroll
  for (int j = 0; j < 8; ++j) {
    GF_ELEM(j, 0, v[j].x)
    GF_ELEM(j, 1, v[j].y)
    GF_ELEM(j, 2, v[j].z)
    GF_ELEM(j, 3, v[j].w)
  }
#undef GF_ELEM

  // convert lane sums to f64, 4-step f64 butterfly over the 16-lane groups
  double d0 = (double)s0, d1 = (double)s1, d2 = (double)s2, d3 = (double)s3;
  double d4 = (double)s4, e0 = (double)t0, e1 = (double)t1, e2 = (double)t2;
#pragma unroll
  for (int m = 8; m >= 1; m >>= 1) {
    d0 += __shfl_xor(d0, m, 64);
    d1 += __shfl_xor(d1, m, 64);
    d2 += __shfl_xor(d2, m, 64);
    d3 += __shfl_xor(d3, m, 64);
    d4 += __shfl_xor(d4, m, 64);
    e0 += __shfl_xor(e0, m, 64);
    e1 += __shfl_xor(e1, m, 64);
    e2 += __shfl_xor(e2, m, 64);
  }

  if (sub == 0) {   // lanes 0,16,32,48 — one per row
    // unscale: multiply by exact powers of 512 (exact f64 ops)
    const double s_y2    = d0;
    const double s_xy2   = d1 * 512.0;
    const double s_x2y2  = d2 * 262144.0;            // 512^2
    const double s_x3y2  = d3 * 134217728.0;         // 512^3
    const double s_x4y2  = d4 * 68719476736.0;       // 512^4
    const double s_y2l   = e0;
    const double s_xy2l  = e1 * 512.0;
    const double s_x2y2l = e2 * 262144.0;
    const double A2 = s_x2y2 * s_x2y2;
    double b_num = A2 * s_xy2l - s_y2 * s_x4y2 * s_xy2l
                 + s_xy2 * s_x4y2 * s_y2l + s_y2 * s_x3y2 * s_x2y2l
                 - s_x2y2 * s_x3y2 * s_y2l - s_xy2 * s_x2y2 * s_x2y2l;
    double c_num = s_x2y2l * s_xy2 * s_xy2 - s_xy2l * s_xy2 * s_x2y2
                 - s_x3y2 * s_y2l * s_xy2 + s_y2l * A2
                 - s_y2 * s_x2y2l * s_x2y2 + s_y2 * s_x3y2 * s_xy2l;
    if (fabs(c_num) < STAB) {
      c_num = (c_num > 0.0) ? STAB : ((c_num < 0.0) ? -STAB : 0.0);
    }
    const double mu = -b_num / (2.0 * c_num);
    const double c_din = s_x4y2 * s_xy2 * s_xy2
                       - 2.0 * s_xy2 * s_x2y2 * s_x3y2 + s_x2y2 * A2
                       - s_y2 * s_x4y2 * s_x2y2 + s_y2 * s_x3y2 * s_x3y2;
    double sigma = -0.5 * c_din / c_num;
    if (sigma < 1.0) sigma = 1.0;  // NaN stays NaN, matching jnp.where
    mu_out[row]  = (float)mu;
    sig_out[row] = (float)sigma;
  }
}

// ---------------------------------------------------------------------------
// Kernel 2: per-batch tridiagonal solve via parallel cyclic reduction (f64).
// Ping-pong buffers -> ONE barrier per step; shared reciprocal R = 1/B
// replaces two divides per step; final divide becomes a multiply.
// ---------------------------------------------------------------------------
__global__ __launch_bounds__(1024) void pcr_solve_kernel(
    const float* __restrict__ mu, const float* __restrict__ sigma,
    const float* __restrict__ w_comp, float* __restrict__ out) {
  __shared__ double A[2][XLEN], B[2][XLEN], C[2][XLEN], D[2][XLEN], R[2][XLEN];
  const int i = threadIdx.x;
  const int g = blockIdx.x * XLEN + i;

  const float w = w_comp[0];
  const float offf  = -2.0f * w;
  const float mainw = (i == 0 || i == XLEN - 1) ? (2.0f * w) : (4.0f * w);
  const float sr = 1.0f / sigma[g];      // f32, matches reference
  const float bf = mainw + sr;           // f32 diag entry
  const float df = mu[g] * sr;           // f32 rhs

  A[0][i] = (i == 0) ? 0.0 : (double)offf;
  C[0][i] = (i == XLEN - 1) ? 0.0 : (double)offf;
  B[0][i] = (double)bf;
  D[0][i] = (double)df;
  R[0][i] = 1.0 / (double)bf;
  __syncthreads();

  int cur = 0;
  for (int s = 1; s < XLEN; s <<= 1) {
    const double ai = A[cur][i], bi = B[cur][i], ci = C[cur][i], di = D[cur][i];
    double am = 0.0, cm = 0.0, dm = 0.0, rm = 0.0;
    double ap = 0.0, cp = 0.0, dp = 0.0, rp = 0.0;
    if (i >= s) {
      am = A[cur][i - s]; cm = C[cur][i - s]; dm = D[cur][i - s]; rm = R[cur][i - s];
    }
    if (i + s < XLEN) {
      ap = A[cur][i + s]; cp = C[cur][i + s]; dp = D[cur][i + s]; rp = R[cur][i + s];
    }
    const double k1 = ai * rm;   // rm/rp are 0 when guarded out
    const double k2 = ci * rp;
    const double nb = bi - k1 * cm - k2 * ap;
    const double nd = di - k1 * dm - k2 * dp;
    const int nxt = cur ^ 1;
    A[nxt][i] = -k1 * am;
    C[nxt][i] = -k2 * cp;
    B[nxt][i] = nb;
    D[nxt][i] = nd;
    R[nxt][i] = 1.0 / nb;
    __syncthreads();
    cur = nxt;
  }

  out[g] = (float)(D[cur][i] * R[cur][i]);
}

extern "C" void kernel_launch(void* const* d_in, const int* in_sizes, int n_in,
                              void* d_out, int out_size, void* d_ws, size_t ws_size,
                              hipStream_t stream) {
  const float* x      = (const float*)d_in[0];
  const float* w_comp = (const float*)d_in[1];
  float* out = (float*)d_out;

  float* mu_ws  = (float*)d_ws;
  float* sig_ws = mu_ws + ROWS;

  gaus_fit_kernel<<<ROWS / 16, 256, 0, stream>>>(x, mu_ws, sig_ws);
  pcr_solve_kernel<<<BN, XLEN, 0, stream>>>(mu_ws, sig_ws, w_comp, out);
}

// Round 10
// 32.710 us; speedup vs baseline: 2.6232x; 1.1079x over previous
//
#include <hip/hip_runtime.h>
#include <hip/hip_bf16.h>
#include <math.h>

#define BN 32
#define XLEN 1024
#define COLS 512
#define ROWS (BN * XLEN)   // 32768
#define STAB 1e-15

// ---------------------------------------------------------------------------
// Kernel 1: softmax (f32) -> min-max normalize (f32) -> weighted Gaussian fit.
// 4 rows per wave: 16 lanes per row, 32 columns per lane; 4 waves per
// 256-thread block (16 rows/block, grid 2048 = 8 blocks/CU).
// Numerics (all within the established f32-accumulation noise floor ~2e-6
// rel on the t-sums, which dominates since round 6):
//   - min/max taken on RAW x, then emin = exp(xn-mx), emax = exp(0) = 1.0
//     exactly (hw exp monotone) => pmax = invS bit-identically.
//   - e overwrites v[] in place (single exp per element, no spill pressure).
//   - pn = fmaf(e, CA, CB) with CA = invS*invden, CB = 0.001 - pmin*invden
//     (1-2 ulp vs the unfused form).
//   - lny = __logf(pn) (v_log_f32 + mul): ~1e-6 abs error, ~3e-8 relative
//     contribution to the sums -- 10x below the accumulation noise.
//   - moments accumulate in f32 with x_hat = col/512; f64 16-lane butterfly;
//     exact 512^k unscaling; f64 closed-form + STAB/sigma clamps verbatim.
// ---------------------------------------------------------------------------
__global__ __launch_bounds__(256) void gaus_fit_kernel(
    const float* __restrict__ x, float* __restrict__ mu_out,
    float* __restrict__ sig_out) {
  const int lane = threadIdx.x & 63;
  const int wid  = threadIdx.x >> 6;   // wave 0..3 in block
  const int sub  = lane & 15;          // lane within row-group
  const int row  = blockIdx.x * 16 + wid * 4 + (lane >> 4);

  // Each lane: 8 float4 loads; elem (j,t) covers col 64*j + 4*sub + t.
  const float4* rp = (const float4*)(x + (size_t)row * COLS);
  float4 v[8];
#pragma unroll
  for (int j = 0; j < 8; ++j) v[j] = rp[16 * j + sub];

  // min & max of raw x, 4-step butterflies serve all 4 rows
  float mx = v[0].x, xn = v[0].x;
#pragma unroll
  for (int j = 0; j < 8; ++j) {
    mx = fmaxf(mx, fmaxf(fmaxf(v[j].x, v[j].y), fmaxf(v[j].z, v[j].w)));
    xn = fminf(xn, fminf(fminf(v[j].x, v[j].y), fminf(v[j].z, v[j].w)));
  }
#pragma unroll
  for (int m = 8; m >= 1; m >>= 1) {
    mx = fmaxf(mx, __shfl_xor(mx, m, 64));
    xn = fminf(xn, __shfl_xor(xn, m, 64));
  }

  // pass A: e = exp(x - mx) overwrites v in place; accumulate S
  float S = 0.0f;
#pragma unroll
  for (int j = 0; j < 8; ++j) {
    v[j].x = __expf(v[j].x - mx);
    v[j].y = __expf(v[j].y - mx);
    v[j].z = __expf(v[j].z - mx);
    v[j].w = __expf(v[j].w - mx);
    S += v[j].x + v[j].y + v[j].z + v[j].w;
  }
#pragma unroll
  for (int m = 8; m >= 1; m >>= 1) S += __shfl_xor(S, m, 64);

  const float invS   = 1.0f / S;
  const float emin   = __expf(xn - mx);   // == min over e (hw exp monotone)
  const float pmin   = emin * invS;
  const float pmax   = invS;              // == 1.0f * invS (emax = exp(0) = 1)
  const float invden = 1.0f / (pmax - pmin);
  const float CA     = invS * invden;
  const float CB     = fmaf(-pmin, invden, 0.001f);

  // pass B: all-f32 weighted sums, hardware log
  const float dsub_s = (float)(4 * sub) * (1.0f / 512.0f);
  float s0 = 0.0f, s1 = 0.0f, s2 = 0.0f, s3 = 0.0f, s4 = 0.0f;
  float t0 = 0.0f, t1 = 0.0f, t2 = 0.0f;

#define GF_ELEM(j, t, comp)                                                   \
  {                                                                           \
    const float pn  = fmaf((comp), CA, CB);       /* in [0.001, 1.001] */     \
    const float lny = __logf(pn);                 /* v_log_f32 + mul   */     \
    const float y2  = pn * pn;                                                \
    const float y2l = y2 * lny;                                               \
    const float xh  = dsub_s + (float)(64 * (j) + (t)) * (1.0f / 512.0f);     \
    const float x2  = xh * xh;                                                \
    const float x3  = x2 * xh;                                                \
    const float x4  = x2 * x2;                                                \
    s0 += y2;                                                                 \
    s1 = fmaf(xh, y2, s1);                                                    \
    s2 = fmaf(x2, y2, s2);                                                    \
    s3 = fmaf(x3, y2, s3);                                                    \
    s4 = fmaf(x4, y2, s4);                                                    \
    t0 += y2l;                                                                \
    t1 = fmaf(xh, y2l, t1);                                                   \
    t2 = fmaf(x2, y2l, t2);                                                   \
  }

#pragma unroll
  for (int j = 0; j < 8; ++j) {
    GF_ELEM(j, 0, v[j].x)
    GF_ELEM(j, 1, v[j].y)
    GF_ELEM(j, 2, v[j].z)
    GF_ELEM(j, 3, v[j].w)
  }
#undef GF_ELEM

  // convert lane sums to f64, 4-step f64 butterfly over the 16-lane groups
  double d0 = (double)s0, d1 = (double)s1, d2 = (double)s2, d3 = (double)s3;
  double d4 = (double)s4, e0 = (double)t0, e1 = (double)t1, e2 = (double)t2;
#pragma unroll
  for (int m = 8; m >= 1; m >>= 1) {
    d0 += __shfl_xor(d0, m, 64);
    d1 += __shfl_xor(d1, m, 64);
    d2 += __shfl_xor(d2, m, 64);
    d3 += __shfl_xor(d3, m, 64);
    d4 += __shfl_xor(d4, m, 64);
    e0 += __shfl_xor(e0, m, 64);
    e1 += __shfl_xor(e1, m, 64);
    e2 += __shfl_xor(e2, m, 64);
  }

  if (sub == 0) {   // lanes 0,16,32,48 — one per row
    // unscale: multiply by exact powers of 512 (exact f64 ops)
    const double s_y2    = d0;
    const double s_xy2   = d1 * 512.0;
    const double s_x2y2  = d2 * 262144.0;            // 512^2
    const double s_x3y2  = d3 * 134217728.0;         // 512^3
    const double s_x4y2  = d4 * 68719476736.0;       // 512^4
    const double s_y2l   = e0;
    const double s_xy2l  = e1 * 512.0;
    const double s_x2y2l = e2 * 262144.0;
    const double A2 = s_x2y2 * s_x2y2;
    double b_num = A2 * s_xy2l - s_y2 * s_x4y2 * s_xy2l
                 + s_xy2 * s_x4y2 * s_y2l + s_y2 * s_x3y2 * s_x2y2l
                 - s_x2y2 * s_x3y2 * s_y2l - s_xy2 * s_x2y2 * s_x2y2l;
    double c_num = s_x2y2l * s_xy2 * s_xy2 - s_xy2l * s_xy2 * s_x2y2
                 - s_x3y2 * s_y2l * s_xy2 + s_y2l * A2
                 - s_y2 * s_x2y2l * s_x2y2 + s_y2 * s_x3y2 * s_xy2l;
    if (fabs(c_num) < STAB) {
      c_num = (c_num > 0.0) ? STAB : ((c_num < 0.0) ? -STAB : 0.0);
    }
    const double mu = -b_num / (2.0 * c_num);
    const double c_din = s_x4y2 * s_xy2 * s_xy2
                       - 2.0 * s_xy2 * s_x2y2 * s_x3y2 + s_x2y2 * A2
                       - s_y2 * s_x4y2 * s_x2y2 + s_y2 * s_x3y2 * s_x3y2;
    double sigma = -0.5 * c_din / c_num;
    if (sigma < 1.0) sigma = 1.0;  // NaN stays NaN, matching jnp.where
    mu_out[row]  = (float)mu;
    sig_out[row] = (float)sigma;
  }
}

// ---------------------------------------------------------------------------
// Kernel 2: per-batch tridiagonal solve via parallel cyclic reduction (f64).
// Ping-pong buffers -> ONE barrier per step; shared reciprocal R = 1/B
// replaces two divides per step; final divide becomes a multiply.
// (Byte-identical to round 9, which passed.)
// ---------------------------------------------------------------------------
__global__ __launch_bounds__(1024) void pcr_solve_kernel(
    const float* __restrict__ mu, const float* __restrict__ sigma,
    const float* __restrict__ w_comp, float* __restrict__ out) {
  __shared__ double A[2][XLEN], B[2][XLEN], C[2][XLEN], D[2][XLEN], R[2][XLEN];
  const int i = threadIdx.x;
  const int g = blockIdx.x * XLEN + i;

  const float w = w_comp[0];
  const float offf  = -2.0f * w;
  const float mainw = (i == 0 || i == XLEN - 1) ? (2.0f * w) : (4.0f * w);
  const float sr = 1.0f / sigma[g];      // f32, matches reference
  const float bf = mainw + sr;           // f32 diag entry
  const float df = mu[g] * sr;           // f32 rhs

  A[0][i] = (i == 0) ? 0.0 : (double)offf;
  C[0][i] = (i == XLEN - 1) ? 0.0 : (double)offf;
  B[0][i] = (double)bf;
  D[0][i] = (double)df;
  R[0][i] = 1.0 / (double)bf;
  __syncthreads();

  int cur = 0;
  for (int s = 1; s < XLEN; s <<= 1) {
    const double ai = A[cur][i], bi = B[cur][i], ci = C[cur][i], di = D[cur][i];
    double am = 0.0, cm = 0.0, dm = 0.0, rm = 0.0;
    double ap = 0.0, cp = 0.0, dp = 0.0, rp = 0.0;
    if (i >= s) {
      am = A[cur][i - s]; cm = C[cur][i - s]; dm = D[cur][i - s]; rm = R[cur][i - s];
    }
    if (i + s < XLEN) {
      ap = A[cur][i + s]; cp = C[cur][i + s]; dp = D[cur][i + s]; rp = R[cur][i + s];
    }
    const double k1 = ai * rm;   // rm/rp are 0 when guarded out
    const double k2 = ci * rp;
    const double nb = bi - k1 * cm - k2 * ap;
    const double nd = di - k1 * dm - k2 * dp;
    const int nxt = cur ^ 1;
    A[nxt][i] = -k1 * am;
    C[nxt][i] = -k2 * cp;
    B[nxt][i] = nb;
    D[nxt][i] = nd;
    R[nxt][i] = 1.0 / nb;
    __syncthreads();
    cur = nxt;
  }

  out[g] = (float)(D[cur][i] * R[cur][i]);
}

extern "C" void kernel_launch(void* const* d_in, const int* in_sizes, int n_in,
                              void* d_out, int out_size, void* d_ws, size_t ws_size,
                              hipStream_t stream) {
  const float* x      = (const float*)d_in[0];
  const float* w_comp = (const float*)d_in[1];
  float* out = (float*)d_out;

  float* mu_ws  = (float*)d_ws;
  float* sig_ws = mu_ws + ROWS;

  gaus_fit_kernel<<<ROWS / 16, 256, 0, stream>>>(x, mu_ws, sig_ws);
  pcr_solve_kernel<<<BN, XLEN, 0, stream>>>(mu_ws, sig_ws, w_comp, out);
}

// Round 12
// 26.668 us; speedup vs baseline: 3.2175x; 1.2266x over previous
//
#include <hip/hip_runtime.h>
#include <hip/hip_bf16.h>
#include <math.h>

#define BN 32
#define XLEN 1024
#define COLS 512
#define ROWS (BN * XLEN)   // 32768
#define STAB 1e-15

typedef float v2f __attribute__((ext_vector_type(2)));

// hardware transcendentals via AMDGCN builtins (glibc-collision-free):
//   HW_EXP2(x) = v_exp_f32 = 2^x ;  HW_LOG2(x) = v_log_f32 = log2(x)
#define HW_EXP2(x) __builtin_amdgcn_exp2f(x)
#define HW_LOG2(x) __builtin_amdgcn_logf(x)

// ---------------------------------------------------------------------------
// Kernel 1: softmax (f32) -> min-max normalize (f32) -> weighted Gaussian fit.
// 4 rows per wave: 16 lanes per row, 32 columns per lane (16 packed pairs);
// 4 waves per 256-thread block (16 rows/block, grid 2048 = 8 blocks/CU).
// Pass A and pass B run on float2 vectors so the backend emits packed dual
// f32 VALU ops (v_pk_fma_f32 etc., gfx90a+): ~2x fewer VALU issues in the
// dominant moment-accumulation pass. Numerics class unchanged from round 10
// (f32 accumulation noise dominates; even/odd split + log2-with-late-ln2
// rescale + fma-folded exp2 are all in the accepted 1e-7-relative family):
//   e   = exp2(fma(x, log2e, -mx*log2e))        [== expf(x-mx) to 1 ulp]
//   pn  = fma(e, CA, CB)  in [0.001, 1.001]
//   l2  = HW_LOG2(pn) (raw v_log_f32); ln-scaling applied to the three
//         log-sums once, in f64, at the end.
//   xh  = col/512 advanced by exact pk constants (all values k/512 exact).
//   8 packed f32 accumulators -> per-lane exact f64 hadd -> 4-step f64
//   butterfly -> verbatim f64 closed form + STAB/sigma clamps.
// ---------------------------------------------------------------------------
__global__ __launch_bounds__(256) void gaus_fit_kernel(
    const float* __restrict__ x, float* __restrict__ mu_out,
    float* __restrict__ sig_out) {
  const int lane = threadIdx.x & 63;
  const int wid  = threadIdx.x >> 6;   // wave 0..3 in block
  const int sub  = lane & 15;          // lane within row-group
  const int row  = blockIdx.x * 16 + wid * 4 + (lane >> 4);

  // Each lane: 16 v2f loads (pairs merge to dwordx4); pair k=2j+h covers
  // cols 64*j + 4*sub + {2h, 2h+1}.
  const v2f* rp2 = (const v2f*)(x + (size_t)row * COLS);
  v2f ve[16];
#pragma unroll
  for (int j = 0; j < 8; ++j) {
    ve[2 * j]     = rp2[32 * j + 2 * sub];
    ve[2 * j + 1] = rp2[32 * j + 2 * sub + 1];
  }

  // packed min/max of raw x, then component + 4-step butterfly reduce
  v2f mx2 = ve[0], xn2 = ve[0];
#pragma unroll
  for (int k = 1; k < 16; ++k) {
    mx2 = __builtin_elementwise_max(mx2, ve[k]);
    xn2 = __builtin_elementwise_min(xn2, ve[k]);
  }
  float mx = fmaxf(mx2.x, mx2.y);
  float xn = fminf(xn2.x, xn2.y);
#pragma unroll
  for (int m = 8; m >= 1; m >>= 1) {
    mx = fmaxf(mx, __shfl_xor(mx, m, 64));
    xn = fminf(xn, __shfl_xor(xn, m, 64));
  }

  // pass A: e = exp2(fma(x, log2e, -mxs)) overwrites ve in place; packed sum
  const float LOG2E = 1.44269504089f;
  const float mxs = mx * LOG2E;
  const v2f L2E2 = {LOG2E, LOG2E};
  const v2f NMXS = {-mxs, -mxs};
  v2f S2 = {0.0f, 0.0f};
#pragma unroll
  for (int k = 0; k < 16; ++k) {
    const v2f xs = __builtin_elementwise_fma(ve[k], L2E2, NMXS);
    ve[k].x = HW_EXP2(xs.x);
    ve[k].y = HW_EXP2(xs.y);
    S2 += ve[k];
  }
  float S = S2.x + S2.y;
#pragma unroll
  for (int m = 8; m >= 1; m >>= 1) S += __shfl_xor(S, m, 64);

  const float invS   = 1.0f / S;
  const float emin   = HW_EXP2(fmaf(xn, LOG2E, -mxs));  // == min over e
  const float pmin   = emin * invS;
  const float pmax   = invS;              // emax = exp(0) = 1 exactly
  const float invden = 1.0f / (pmax - pmin);
  const float CA     = invS * invden;
  const float CB     = fmaf(-pmin, invden, 0.001f);
  const v2f CA2 = {CA, CA}, CB2 = {CB, CB};

  // pass B: packed f32 moment accumulation with raw log2
  const float bb = (float)(4 * sub) * (1.0f / 512.0f);
  v2f xh = {bb, bb + 0.001953125f};                 // {b, b + 1/512}, exact
  const v2f ADV1 = {0.00390625f, 0.00390625f};      // +2/512 (within float4)
  const v2f ADV2 = {0.12109375f, 0.12109375f};      // +62/512 (next j)
  v2f u0 = {0, 0}, u1 = {0, 0}, u2 = {0, 0}, u3 = {0, 0}, u4 = {0, 0};
  v2f w0 = {0, 0}, w1 = {0, 0}, w2 = {0, 0};

#define GF_PAIR(k, ADV)                                                       \
  {                                                                           \
    const v2f pn = __builtin_elementwise_fma(ve[k], CA2, CB2);                \
    v2f l2;                                                                   \
    l2.x = HW_LOG2(pn.x);                                                     \
    l2.y = HW_LOG2(pn.y);                                                     \
    const v2f y2  = pn * pn;                                                  \
    const v2f y2l = y2 * l2;                                                  \
    const v2f x2  = xh * xh;                                                  \
    const v2f x3  = x2 * xh;                                                  \
    const v2f x4  = x2 * x2;                                                  \
    u0 += y2;                                                                 \
    u1 = __builtin_elementwise_fma(xh, y2, u1);                               \
    u2 = __builtin_elementwise_fma(x2, y2, u2);                               \
    u3 = __builtin_elementwise_fma(x3, y2, u3);                               \
    u4 = __builtin_elementwise_fma(x4, y2, u4);                               \
    w0 += y2l;                                                                \
    w1 = __builtin_elementwise_fma(xh, y2l, w1);                              \
    w2 = __builtin_elementwise_fma(x2, y2l, w2);                              \
    xh += ADV;                                                                \
  }

#pragma unroll
  for (int j = 0; j < 8; ++j) {
    GF_PAIR(2 * j, ADV1)
    GF_PAIR(2 * j + 1, ADV2)
  }
#undef GF_PAIR

  // per-lane exact f64 hadd of packed sums, then 4-step f64 butterfly
  double d0 = (double)u0.x + (double)u0.y;
  double d1 = (double)u1.x + (double)u1.y;
  double d2 = (double)u2.x + (double)u2.y;
  double d3 = (double)u3.x + (double)u3.y;
  double d4 = (double)u4.x + (double)u4.y;
  double e0 = (double)w0.x + (double)w0.y;
  double e1 = (double)w1.x + (double)w1.y;
  double e2 = (double)w2.x + (double)w2.y;
#pragma unroll
  for (int m = 8; m >= 1; m >>= 1) {
    d0 += __shfl_xor(d0, m, 64);
    d1 += __shfl_xor(d1, m, 64);
    d2 += __shfl_xor(d2, m, 64);
    d3 += __shfl_xor(d3, m, 64);
    d4 += __shfl_xor(d4, m, 64);
    e0 += __shfl_xor(e0, m, 64);
    e1 += __shfl_xor(e1, m, 64);
    e2 += __shfl_xor(e2, m, 64);
  }

  if (sub == 0) {   // lanes 0,16,32,48 — one per row
    const double LN2D = 0.6931471805599453;
    // unscale by exact 512^k; apply ln2 to the log2-sums (one rounding each)
    const double s_y2    = d0;
    const double s_xy2   = d1 * 512.0;
    const double s_x2y2  = d2 * 262144.0;            // 512^2
    const double s_x3y2  = d3 * 134217728.0;         // 512^3
    const double s_x4y2  = d4 * 68719476736.0;       // 512^4
    const double s_y2l   = e0 * LN2D;
    const double s_xy2l  = (e1 * 512.0) * LN2D;
    const double s_x2y2l = (e2 * 262144.0) * LN2D;
    const double A2 = s_x2y2 * s_x2y2;
    double b_num = A2 * s_xy2l - s_y2 * s_x4y2 * s_xy2l
                 + s_xy2 * s_x4y2 * s_y2l + s_y2 * s_x3y2 * s_x2y2l
                 - s_x2y2 * s_x3y2 * s_y2l - s_xy2 * s_x2y2 * s_x2y2l;
    double c_num = s_x2y2l * s_xy2 * s_xy2 - s_xy2l * s_xy2 * s_x2y2
                 - s_x3y2 * s_y2l * s_xy2 + s_y2l * A2
                 - s_y2 * s_x2y2l * s_x2y2 + s_y2 * s_x3y2 * s_xy2l;
    if (fabs(c_num) < STAB) {
      c_num = (c_num > 0.0) ? STAB : ((c_num < 0.0) ? -STAB : 0.0);
    }
    const double mu = -b_num / (2.0 * c_num);
    const double c_din = s_x4y2 * s_xy2 * s_xy2
                       - 2.0 * s_xy2 * s_x2y2 * s_x3y2 + s_x2y2 * A2
                       - s_y2 * s_x4y2 * s_x2y2 + s_y2 * s_x3y2 * s_x3y2;
    double sigma = -0.5 * c_din / c_num;
    if (sigma < 1.0) sigma = 1.0;  // NaN stays NaN, matching jnp.where
    mu_out[row]  = (float)mu;
    sig_out[row] = (float)sigma;
  }
}

// ---------------------------------------------------------------------------
// Kernel 2: per-batch tridiagonal solve via parallel cyclic reduction (f64).
// Ping-pong buffers -> ONE barrier per step; shared reciprocal R = 1/B
// replaces two divides per step; final divide becomes a multiply.
// (Byte-identical to round 10, which passed.)
// ---------------------------------------------------------------------------
__global__ __launch_bounds__(1024) void pcr_solve_kernel(
    const float* __restrict__ mu, const float* __restrict__ sigma,
    const float* __restrict__ w_comp, float* __restrict__ out) {
  __shared__ double A[2][XLEN], B[2][XLEN], C[2][XLEN], D[2][XLEN], R[2][XLEN];
  const int i = threadIdx.x;
  const int g = blockIdx.x * XLEN + i;

  const float w = w_comp[0];
  const float offf  = -2.0f * w;
  const float mainw = (i == 0 || i == XLEN - 1) ? (2.0f * w) : (4.0f * w);
  const float sr = 1.0f / sigma[g];      // f32, matches reference
  const float bf = mainw + sr;           // f32 diag entry
  const float df = mu[g] * sr;           // f32 rhs

  A[0][i] = (i == 0) ? 0.0 : (double)offf;
  C[0][i] = (i == XLEN - 1) ? 0.0 : (double)offf;
  B[0][i] = (double)bf;
  D[0][i] = (double)df;
  R[0][i] = 1.0 / (double)bf;
  __syncthreads();

  int cur = 0;
  for (int s = 1; s < XLEN; s <<= 1) {
    const double ai = A[cur][i], bi = B[cur][i], ci = C[cur][i], di = D[cur][i];
    double am = 0.0, cm = 0.0, dm = 0.0, rm = 0.0;
    double ap = 0.0, cp = 0.0, dp = 0.0, rp = 0.0;
    if (i >= s) {
      am = A[cur][i - s]; cm = C[cur][i - s]; dm = D[cur][i - s]; rm = R[cur][i - s];
    }
    if (i + s < XLEN) {
      ap = A[cur][i + s]; cp = C[cur][i + s]; dp = D[cur][i + s]; rp = R[cur][i + s];
    }
    const double k1 = ai * rm;   // rm/rp are 0 when guarded out
    const double k2 = ci * rp;
    const double nb = bi - k1 * cm - k2 * ap;
    const double nd = di - k1 * dm - k2 * dp;
    const int nxt = cur ^ 1;
    A[nxt][i] = -k1 * am;
    C[nxt][i] = -k2 * cp;
    B[nxt][i] = nb;
    D[nxt][i] = nd;
    R[nxt][i] = 1.0 / nb;
    __syncthreads();
    cur = nxt;
  }

  out[g] = (float)(D[cur][i] * R[cur][i]);
}

extern "C" void kernel_launch(void* const* d_in, const int* in_sizes, int n_in,
                              void* d_out, int out_size, void* d_ws, size_t ws_size,
                              hipStream_t stream) {
  const float* x      = (const float*)d_in[0];
  const float* w_comp = (const float*)d_in[1];
  float* out = (float*)d_out;

  float* mu_ws  = (float*)d_ws;
  float* sig_ws = mu_ws + ROWS;

  gaus_fit_kernel<<<ROWS / 16, 256, 0, stream>>>(x, mu_ws, sig_ws);
  pcr_solve_kernel<<<BN, XLEN, 0, stream>>>(mu_ws, sig_ws, w_comp, out);
}

// Round 13
// 25.643 us; speedup vs baseline: 3.3462x; 1.0400x over previous
//
#include <hip/hip_runtime.h>
#include <hip/hip_bf16.h>
#include <math.h>

#define BN 32
#define XLEN 1024
#define COLS 512
#define ROWS (BN * XLEN)   // 32768
#define STAB 1e-15

typedef float v2f __attribute__((ext_vector_type(2)));

// hardware transcendentals via AMDGCN builtins (glibc-collision-free):
//   HW_EXP2(x) = v_exp_f32 = 2^x ;  HW_LOG2(x) = v_log_f32 = log2(x)
#define HW_EXP2(x) __builtin_amdgcn_exp2f(x)
#define HW_LOG2(x) __builtin_amdgcn_logf(x)

// ---------------------------------------------------------------------------
// Kernel 1: softmax (f32) -> min-max normalize (f32) -> weighted Gaussian fit.
// 4 rows per wave: 16 lanes per row, 32 columns per lane (16 packed pairs);
// 4 waves per 256-thread block (16 rows/block, grid 2048 = 8 blocks/CU).
// float2 arithmetic -> packed dual-f32 VALU (v_pk_fma_f32 etc.).
// This round: xh is computed per-pair from a compile-time constant offset
// (exact multiples of 1/512) instead of a serial += chain -> all 16 pairs'
// power/moment chains are independent (16-way ILP). Values bit-identical.
// Numerics otherwise identical to round 12 (passed):
//   e = exp2(fma(x,log2e,-mxs)); pn = fma(e,CA,CB); l2 = v_log_f32(pn);
//   ln2 applied to the three log-sums once in f64 at the end; f32 packed
//   accumulators -> exact f64 hadd -> 4-step f64 butterfly -> verbatim f64
//   closed form + STAB/sigma clamps.
// ---------------------------------------------------------------------------
__global__ __launch_bounds__(256) void gaus_fit_kernel(
    const float* __restrict__ x, float* __restrict__ mu_out,
    float* __restrict__ sig_out) {
  const int lane = threadIdx.x & 63;
  const int wid  = threadIdx.x >> 6;   // wave 0..3 in block
  const int sub  = lane & 15;          // lane within row-group
  const int row  = blockIdx.x * 16 + wid * 4 + (lane >> 4);

  // Each lane: 16 v2f loads (adjacent pairs merge to dwordx4); pair k=2j+h
  // covers cols 64*j + 4*sub + {2h, 2h+1}.
  const v2f* rp2 = (const v2f*)(x + (size_t)row * COLS);
  v2f ve[16];
#pragma unroll
  for (int j = 0; j < 8; ++j) {
    ve[2 * j]     = rp2[32 * j + 2 * sub];
    ve[2 * j + 1] = rp2[32 * j + 2 * sub + 1];
  }

  // packed min/max of raw x, then component + 4-step butterfly reduce
  v2f mx2 = ve[0], xn2 = ve[0];
#pragma unroll
  for (int k = 1; k < 16; ++k) {
    mx2 = __builtin_elementwise_max(mx2, ve[k]);
    xn2 = __builtin_elementwise_min(xn2, ve[k]);
  }
  float mx = fmaxf(mx2.x, mx2.y);
  float xn = fminf(xn2.x, xn2.y);
#pragma unroll
  for (int m = 8; m >= 1; m >>= 1) {
    mx = fmaxf(mx, __shfl_xor(mx, m, 64));
    xn = fminf(xn, __shfl_xor(xn, m, 64));
  }

  // pass A: e = exp2(fma(x, log2e, -mxs)) overwrites ve in place; packed sum
  const float LOG2E = 1.44269504089f;
  const float mxs = mx * LOG2E;
  const v2f L2E2 = {LOG2E, LOG2E};
  const v2f NMXS = {-mxs, -mxs};
  v2f S2 = {0.0f, 0.0f};
#pragma unroll
  for (int k = 0; k < 16; ++k) {
    const v2f xs = __builtin_elementwise_fma(ve[k], L2E2, NMXS);
    ve[k].x = HW_EXP2(xs.x);
    ve[k].y = HW_EXP2(xs.y);
    S2 += ve[k];
  }
  float S = S2.x + S2.y;
#pragma unroll
  for (int m = 8; m >= 1; m >>= 1) S += __shfl_xor(S, m, 64);

  const float invS   = 1.0f / S;
  const float emin   = HW_EXP2(fmaf(xn, LOG2E, -mxs));  // == min over e
  const float pmin   = emin * invS;
  const float pmax   = invS;              // emax = exp(0) = 1 exactly
  const float invden = 1.0f / (pmax - pmin);
  const float CA     = invS * invden;
  const float CB     = fmaf(-pmin, invden, 0.001f);
  const v2f CA2 = {CA, CA}, CB2 = {CB, CB};

  // pass B: packed f32 moment accumulation with raw log2.
  // xh per pair = bb + compile-time-constant offset (exact): no serial chain.
  const float bb = (float)(4 * sub) * (1.0f / 512.0f);
  v2f u0 = {0, 0}, u1 = {0, 0}, u2 = {0, 0}, u3 = {0, 0}, u4 = {0, 0};
  v2f w0 = {0, 0}, w1 = {0, 0}, w2 = {0, 0};

#define GF_PAIR(j, h)                                                         \
  {                                                                           \
    const int   k   = 2 * (j) + (h);                                          \
    const float off = (float)(64 * (j) + 2 * (h)) * (1.0f / 512.0f);          \
    const v2f xh = {bb + off, bb + off + 0.001953125f};                       \
    const v2f pn = __builtin_elementwise_fma(ve[k], CA2, CB2);                \
    v2f l2;                                                                   \
    l2.x = HW_LOG2(pn.x);                                                     \
    l2.y = HW_LOG2(pn.y);                                                     \
    const v2f y2  = pn * pn;                                                  \
    const v2f y2l = y2 * l2;                                                  \
    const v2f x2  = xh * xh;                                                  \
    const v2f x3  = x2 * xh;                                                  \
    const v2f x4  = x2 * x2;                                                  \
    u0 += y2;                                                                 \
    u1 = __builtin_elementwise_fma(xh, y2, u1);                               \
    u2 = __builtin_elementwise_fma(x2, y2, u2);                               \
    u3 = __builtin_elementwise_fma(x3, y2, u3);                               \
    u4 = __builtin_elementwise_fma(x4, y2, u4);                               \
    w0 += y2l;                                                                \
    w1 = __builtin_elementwise_fma(xh, y2l, w1);                              \
    w2 = __builtin_elementwise_fma(x2, y2l, w2);                              \
  }

#pragma unroll
  for (int j = 0; j < 8; ++j) {
    GF_PAIR(j, 0)
    GF_PAIR(j, 1)
  }
#undef GF_PAIR

  // per-lane exact f64 hadd of packed sums, then 4-step f64 butterfly
  double d0 = (double)u0.x + (double)u0.y;
  double d1 = (double)u1.x + (double)u1.y;
  double d2 = (double)u2.x + (double)u2.y;
  double d3 = (double)u3.x + (double)u3.y;
  double d4 = (double)u4.x + (double)u4.y;
  double e0 = (double)w0.x + (double)w0.y;
  double e1 = (double)w1.x + (double)w1.y;
  double e2 = (double)w2.x + (double)w2.y;
#pragma unroll
  for (int m = 8; m >= 1; m >>= 1) {
    d0 += __shfl_xor(d0, m, 64);
    d1 += __shfl_xor(d1, m, 64);
    d2 += __shfl_xor(d2, m, 64);
    d3 += __shfl_xor(d3, m, 64);
    d4 += __shfl_xor(d4, m, 64);
    e0 += __shfl_xor(e0, m, 64);
    e1 += __shfl_xor(e1, m, 64);
    e2 += __shfl_xor(e2, m, 64);
  }

  if (sub == 0) {   // lanes 0,16,32,48 — one per row
    const double LN2D = 0.6931471805599453;
    // unscale by exact 512^k; apply ln2 to the log2-sums (one rounding each)
    const double s_y2    = d0;
    const double s_xy2   = d1 * 512.0;
    const double s_x2y2  = d2 * 262144.0;            // 512^2
    const double s_x3y2  = d3 * 134217728.0;         // 512^3
    const double s_x4y2  = d4 * 68719476736.0;       // 512^4
    const double s_y2l   = e0 * LN2D;
    const double s_xy2l  = (e1 * 512.0) * LN2D;
    const double s_x2y2l = (e2 * 262144.0) * LN2D;
    const double A2 = s_x2y2 * s_x2y2;
    double b_num = A2 * s_xy2l - s_y2 * s_x4y2 * s_xy2l
                 + s_xy2 * s_x4y2 * s_y2l + s_y2 * s_x3y2 * s_x2y2l
                 - s_x2y2 * s_x3y2 * s_y2l - s_xy2 * s_x2y2 * s_x2y2l;
    double c_num = s_x2y2l * s_xy2 * s_xy2 - s_xy2l * s_xy2 * s_x2y2
                 - s_x3y2 * s_y2l * s_xy2 + s_y2l * A2
                 - s_y2 * s_x2y2l * s_x2y2 + s_y2 * s_x3y2 * s_xy2l;
    if (fabs(c_num) < STAB) {
      c_num = (c_num > 0.0) ? STAB : ((c_num < 0.0) ? -STAB : 0.0);
    }
    const double mu = -b_num / (2.0 * c_num);
    const double c_din = s_x4y2 * s_xy2 * s_xy2
                       - 2.0 * s_xy2 * s_x2y2 * s_x3y2 + s_x2y2 * A2
                       - s_y2 * s_x4y2 * s_x2y2 + s_y2 * s_x3y2 * s_x3y2;
    double sigma = -0.5 * c_din / c_num;
    if (sigma < 1.0) sigma = 1.0;  // NaN stays NaN, matching jnp.where
    mu_out[row]  = (float)mu;
    sig_out[row] = (float)sigma;
  }
}

// ---------------------------------------------------------------------------
// Kernel 2: per-batch tridiagonal solve via parallel cyclic reduction, f32.
// The reference itself inverts this matrix in f32 (jnp.linalg.inv on a f32
// hess) -- f32 PCR on a diagonally dominant system is the same error class
// (~1e-6 rel). Halves LDS traffic and runs ALU at full f32 rate.
// Ping-pong buffers -> ONE barrier per step; shared reciprocal R = 1/B;
// final divide is a multiply.
// ---------------------------------------------------------------------------
__global__ __launch_bounds__(1024) void pcr_solve_kernel(
    const float* __restrict__ mu, const float* __restrict__ sigma,
    const float* __restrict__ w_comp, float* __restrict__ out) {
  __shared__ float A[2][XLEN], B[2][XLEN], C[2][XLEN], D[2][XLEN], R[2][XLEN];
  const int i = threadIdx.x;
  const int g = blockIdx.x * XLEN + i;

  const float w = w_comp[0];
  const float offf  = -2.0f * w;
  const float mainw = (i == 0 || i == XLEN - 1) ? (2.0f * w) : (4.0f * w);
  const float sr = 1.0f / sigma[g];      // f32, matches reference
  const float bf = mainw + sr;           // f32 diag entry
  const float df = mu[g] * sr;           // f32 rhs

  A[0][i] = (i == 0) ? 0.0f : offf;
  C[0][i] = (i == XLEN - 1) ? 0.0f : offf;
  B[0][i] = bf;
  D[0][i] = df;
  R[0][i] = 1.0f / bf;
  __syncthreads();

  int cur = 0;
  for (int s = 1; s < XLEN; s <<= 1) {
    const float ai = A[cur][i], bi = B[cur][i], ci = C[cur][i], di = D[cur][i];
    float am = 0.0f, cm = 0.0f, dm = 0.0f, rm = 0.0f;
    float ap = 0.0f, cp = 0.0f, dp = 0.0f, rp = 0.0f;
    if (i >= s) {
      am = A[cur][i - s]; cm = C[cur][i - s]; dm = D[cur][i - s]; rm = R[cur][i - s];
    }
    if (i + s < XLEN) {
      ap = A[cur][i + s]; cp = C[cur][i + s]; dp = D[cur][i + s]; rp = R[cur][i + s];
    }
    const float k1 = ai * rm;   // rm/rp are 0 when guarded out
    const float k2 = ci * rp;
    const float nb = bi - k1 * cm - k2 * ap;
    const float nd = di - k1 * dm - k2 * dp;
    const int nxt = cur ^ 1;
    A[nxt][i] = -k1 * am;
    C[nxt][i] = -k2 * cp;
    B[nxt][i] = nb;
    D[nxt][i] = nd;
    R[nxt][i] = 1.0f / nb;
    __syncthreads();
    cur = nxt;
  }

  out[g] = D[cur][i] * R[cur][i];
}

extern "C" void kernel_launch(void* const* d_in, const int* in_sizes, int n_in,
                              void* d_out, int out_size, void* d_ws, size_t ws_size,
                              hipStream_t stream) {
  const float* x      = (const float*)d_in[0];
  const float* w_comp = (const float*)d_in[1];
  float* out = (float*)d_out;

  float* mu_ws  = (float*)d_ws;
  float* sig_ws = mu_ws + ROWS;

  gaus_fit_kernel<<<ROWS / 16, 256, 0, stream>>>(x, mu_ws, sig_ws);
  pcr_solve_kernel<<<BN, XLEN, 0, stream>>>(mu_ws, sig_ws, w_comp, out);
}